// Round 2
// baseline (813.399 us; speedup 1.0000x reference)
//
#include <hip/hip_runtime.h>

#define BT 51200      // B*T
#define NB 512        // batch

// ---------- workspace float offsets ----------
#define P1_OFF   ((size_t)0)
#define X_OFF    ((size_t)20480000)
#define GX_OFF   ((size_t)0)
#define SM_OFF   ((size_t)27033600)

__device__ __forceinline__ float sigf(float x) {
  return __fdividef(1.f, 1.f + __expf(-x));
}
__device__ __forceinline__ float tanhf2(float x) {
  float ax = fabsf(x);
  float e = __expf(-2.f * ax);
  float r = __fdividef(1.f - e, 1.f + e);
  return x < 0.f ? -r : r;
}

// ================= K1: conv1 (SAME 3x3, C=4->16) + relu + 2x2 maxpool =====
// 32 items/block, 256 threads: item = tid&31, grp = tid>>5 (8 grp x 2 oc).
// All 5 pooled rows in ONE block (full obs reuse, read exactly once,
// coalesced float4 staging). LDS 51.3KB -> 3 blocks/CU = 12 waves/CU.
// xs stride 401: bank = 17*item mod 32 = permutation -> conflict-free;
// lanes 32..63 mirror lanes 0..31 addrs -> broadcast (free).
__global__ __launch_bounds__(256, 3)
void k1_conv1(const float* __restrict__ obs, const float* __restrict__ w,
              const float* __restrict__ bias, float* __restrict__ p1) {
  __shared__ float xs[32 * 401];
  int tid = threadIdx.x;
  int i0 = blockIdx.x * 32;
  // stage 32 items x 400 floats, float4-vectorized, fully coalesced
  for (int idx = tid; idx < 3200; idx += 256) {
    int item = idx / 100, f = idx - item * 100;
    float4 v = ((const float4*)obs)[(size_t)(i0 + item) * 100 + f];
    float* d = xs + item * 401 + f * 4;
    d[0] = v.x; d[1] = v.y; d[2] = v.z; d[3] = v.w;
  }
  __syncthreads();
  int item = tid & 31;
  int grp = tid >> 5;  // 0..7 -> out channels {2g, 2g+1}
  const float* xrow = xs + item * 401;
#pragma unroll 1
  for (int p = 0; p < 5; ++p) {
    float acc[2][5][2][2];
#pragma unroll
    for (int u = 0; u < 2; ++u) {
      float bv = bias[grp * 2 + u];
#pragma unroll
      for (int q = 0; q < 5; ++q)
#pragma unroll
        for (int ii = 0; ii < 2; ++ii)
#pragma unroll
          for (int jj = 0; jj < 2; ++jj) acc[u][q][ii][jj] = bv;
    }
#pragma unroll 1
    for (int c = 0; c < 4; ++c) {
      float rows[4][12];
#pragma unroll
      for (int rr = 0; rr < 4; ++rr) {
        int r = 2 * p - 1 + rr;
        rows[rr][0] = 0.f;
        rows[rr][11] = 0.f;
        if (r >= 0 && r <= 9) {
#pragma unroll
          for (int j = 0; j < 10; ++j) rows[rr][j + 1] = xrow[c * 100 + r * 10 + j];
        } else {
#pragma unroll
          for (int j = 0; j < 10; ++j) rows[rr][j + 1] = 0.f;
        }
      }
#pragma unroll
      for (int u = 0; u < 2; ++u) {
        int o = grp * 2 + u;
        const float* wp = w + o * 36 + c * 9;
        float w00 = wp[0], w01 = wp[1], w02 = wp[2];
        float w10 = wp[3], w11 = wp[4], w12 = wp[5];
        float w20 = wp[6], w21 = wp[7], w22 = wp[8];
#pragma unroll
        for (int q = 0; q < 5; ++q) {
#pragma unroll
          for (int ii = 0; ii < 2; ++ii) {
#pragma unroll
            for (int jj = 0; jj < 2; ++jj) {
              float a = acc[u][q][ii][jj];
              int cb = 2 * q + jj;
              a += rows[ii][cb] * w00 + rows[ii][cb + 1] * w01 + rows[ii][cb + 2] * w02;
              a += rows[ii + 1][cb] * w10 + rows[ii + 1][cb + 1] * w11 + rows[ii + 1][cb + 2] * w12;
              a += rows[ii + 2][cb] * w20 + rows[ii + 2][cb + 1] * w21 + rows[ii + 2][cb + 2] * w22;
              acc[u][q][ii][jj] = a;
            }
          }
        }
      }
    }
#pragma unroll
    for (int u = 0; u < 2; ++u) {
      int o = grp * 2 + u;
#pragma unroll
      for (int q = 0; q < 5; ++q) {
        float m = fmaxf(fmaxf(acc[u][q][0][0], acc[u][q][0][1]),
                        fmaxf(acc[u][q][1][0], acc[u][q][1][1]));
        m = fmaxf(m, 0.f);
        p1[(size_t)(o * 25 + p * 5 + q) * BT + i0 + item] = m;
      }
    }
  }
}

// ================= K2: conv2 (SAME 3x3, 16->32) + relu + 2x2 maxpool ======
__global__ __launch_bounds__(256, 2)
void k2_conv2(const float* __restrict__ p1, const float* __restrict__ w,
              const float* __restrict__ bias, float* __restrict__ x) {
  int item = blockIdx.x * 256 + threadIdx.x;
  int oc = blockIdx.y;
  float acc[8][16];
#pragma unroll
  for (int o = 0; o < 8; ++o) {
    float bv = bias[oc * 8 + o];
#pragma unroll
    for (int pos = 0; pos < 16; ++pos) acc[o][pos] = bv;
  }
#pragma unroll 1
  for (int c = 0; c < 16; ++c) {
    float in[6][6];
#pragma unroll
    for (int t = 0; t < 6; ++t) { in[0][t] = 0.f; in[t][0] = 0.f; }
#pragma unroll
    for (int i = 0; i < 5; ++i)
#pragma unroll
      for (int j = 0; j < 5; ++j)
        in[i + 1][j + 1] = p1[(size_t)(c * 25 + i * 5 + j) * BT + item];
#pragma unroll
    for (int o = 0; o < 8; ++o) {
#pragma unroll
      for (int i = 0; i < 4; ++i)
#pragma unroll
        for (int j = 0; j < 4; ++j) {
          float a = acc[o][i * 4 + j];
#pragma unroll
          for (int dr = 0; dr < 3; ++dr)
#pragma unroll
            for (int dj = 0; dj < 3; ++dj)
              a += in[i + dr][j + dj] * w[((oc * 8 + o) * 16 + c) * 9 + dr * 3 + dj];
          acc[o][i * 4 + j] = a;
        }
    }
  }
#pragma unroll
  for (int o = 0; o < 8; ++o)
#pragma unroll
    for (int p = 0; p < 2; ++p)
#pragma unroll
      for (int q = 0; q < 2; ++q) {
        float m = fmaxf(fmaxf(acc[o][(2 * p) * 4 + 2 * q], acc[o][(2 * p) * 4 + 2 * q + 1]),
                        fmaxf(acc[o][(2 * p + 1) * 4 + 2 * q], acc[o][(2 * p + 1) * 4 + 2 * q + 1]));
        m = fmaxf(m, 0.f);
        x[(size_t)((oc * 8 + o) * 4 + p * 2 + q) * BT + item] = m;
      }
}

// ================= K3: fc1(+bn,relu) -> fc2(+bn,relu) -> eWih projection ===
__global__ __launch_bounds__(256, 2)
void k3_fc(const float* __restrict__ x,
           const float* __restrict__ f1w, const float* __restrict__ f1b,
           const float* __restrict__ bn1g, const float* __restrict__ bn1b,
           const float* __restrict__ f2w, const float* __restrict__ f2b,
           const float* __restrict__ bn2g, const float* __restrict__ bn2b,
           const float* __restrict__ eWih, const float* __restrict__ ebih,
           const float* __restrict__ ebhh, float* __restrict__ gx) {
  __shared__ float xs[128 * 64];
  __shared__ float ys[128 * 64];
  const float BNRS = 0.9999950000374997f;  // 1/sqrt(1+1e-5)
  int tid = threadIdx.x;
  int lane = tid & 63;
  int wv = __builtin_amdgcn_readfirstlane(tid >> 6);
  int i0 = blockIdx.x * 64;
#pragma unroll
  for (int r = 0; r < 32; ++r) {
    int k = r * 4 + (tid >> 6);
    xs[k * 64 + lane] = x[(size_t)k * BT + i0 + lane];
  }
  __syncthreads();
#pragma unroll 1
  for (int jj = 0; jj < 8; ++jj) {
    int j0 = wv * 32 + jj * 4;
    float a[4] = {0.f, 0.f, 0.f, 0.f};
#pragma unroll 8
    for (int k = 0; k < 128; ++k) {
      float xv = xs[k * 64 + lane];
#pragma unroll
      for (int u = 0; u < 4; ++u) a[u] += xv * f1w[(j0 + u) * 128 + k];
    }
#pragma unroll
    for (int u = 0; u < 4; ++u) {
      int j = j0 + u;
      float v = a[u] + f1b[j];
      v = bn1g[j] * v * BNRS + bn1b[j];
      ys[j * 64 + lane] = fmaxf(v, 0.f);
    }
  }
  __syncthreads();
#pragma unroll 1
  for (int jj = 0; jj < 4; ++jj) {
    int j0 = wv * 16 + jj * 4;
    float a[4] = {0.f, 0.f, 0.f, 0.f};
#pragma unroll 8
    for (int k = 0; k < 128; ++k) {
      float yv = ys[k * 64 + lane];
#pragma unroll
      for (int u = 0; u < 4; ++u) a[u] += yv * f2w[(j0 + u) * 128 + k];
    }
#pragma unroll
    for (int u = 0; u < 4; ++u) {
      int j = j0 + u;
      float v = a[u] + f2b[j];
      v = bn2g[j] * v * BNRS + bn2b[j];
      xs[j * 64 + lane] = fmaxf(v, 0.f);
    }
  }
  __syncthreads();
#pragma unroll 1
  for (int jj = 0; jj < 8; ++jj) {
    int j0 = wv * 32 + jj * 4;
    float a[4] = {0.f, 0.f, 0.f, 0.f};
#pragma unroll 8
    for (int k = 0; k < 64; ++k) {
      float zv = xs[k * 64 + lane];
#pragma unroll
      for (int u = 0; u < 4; ++u) a[u] += zv * eWih[(j0 + u) * 64 + k];
    }
#pragma unroll
    for (int u = 0; u < 4; ++u) {
      int j = j0 + u;
      gx[(size_t)j * BT + i0 + lane] = a[u] + ebih[j] + ebhh[j];
    }
  }
}

// ================= K4: encoder LSTM (T=100), one wave per batch ===========
__global__ __launch_bounds__(64, 4)
void k4_enc(const float* __restrict__ gx, const float* __restrict__ eWhh,
            float* __restrict__ dh, float* __restrict__ dc) {
  __shared__ float wT[32 * 128];  // [k][gate]
  int lane = threadIdx.x;
  int b = blockIdx.x;
#pragma unroll 1
  for (int r = 0; r < 64; ++r) {
    int idx = lane + r * 64;
    int g = idx & 127, k = idx >> 7;
    wT[k * 128 + g] = eWhh[g * 32 + k];
  }
  __syncthreads();
  float c = 0.f, h = 0.f;
  size_t base0 = (size_t)b * 100;
  float ga_n = gx[(size_t)lane * BT + base0];
  float gb_n = gx[(size_t)(lane + 64) * BT + base0];
  int xl = (lane & 31) + 32;
#pragma unroll 1
  for (int t = 0; t < 100; ++t) {
    float ga = ga_n, gb2 = gb_n;
    if (t < 99) {
      ga_n = gx[(size_t)lane * BT + base0 + t + 1];
      gb_n = gx[(size_t)(lane + 64) * BT + base0 + t + 1];
    }
#pragma unroll
    for (int k = 0; k < 32; ++k) {
      float hk = __shfl(h, k);
      ga += hk * wT[k * 128 + lane];
      gb2 += hk * wT[k * 128 + lane + 64];
    }
    float gaX = __shfl(ga, xl);   // gate lane+32 (f for lanes<32)
    float gbX = __shfl(gb2, xl);  // gate lane+96 (o for lanes<32)
    if (lane < 32) {
      float ig = sigf(ga);
      float fg = sigf(gaX);
      float gg = tanhf2(gb2);
      float og = sigf(gbX);
      c = fg * c + ig * gg;
      h = og * tanhf2(c);
    }
  }
  if (lane < 32) {
    dh[b * 32 + lane] = h;
    dc[b * 32 + lane] = c;
  }
}

// ====== K5: decoder LSTM (din==dh identity) + physics + Q/R LSTMs =========
__global__ __launch_bounds__(256, 2)
void k5_dec(const float* __restrict__ obs,
            const float* __restrict__ dWih, const float* __restrict__ dWhh,
            const float* __restrict__ dbih, const float* __restrict__ dbhh,
            const float* __restrict__ ow, const float* __restrict__ ob,
            const float* __restrict__ qWih, const float* __restrict__ qWhh,
            const float* __restrict__ qbih, const float* __restrict__ qbhh,
            const float* __restrict__ qfw, const float* __restrict__ qfb,
            const float* __restrict__ rWih, const float* __restrict__ rWhh,
            const float* __restrict__ rbih, const float* __restrict__ rbhh,
            const float* __restrict__ rfw, const float* __restrict__ rfb,
            const float* __restrict__ dh0, const float* __restrict__ dc0,
            float* __restrict__ traj, float* __restrict__ qdg, float* __restrict__ rdg) {
  __shared__ float dwT[32 * 128], qihT[24 * 128], qhhT[32 * 128], rihT[24 * 128], rhhT[32 * 128];
  __shared__ float owT[32 * 12], qfwT[32 * 24], rfwT[32 * 24];
  __shared__ float dbs[128], qbs[128], rbs[128];
  __shared__ float tL4[4 * 120];
  int tid = threadIdx.x;
  for (int idx = tid; idx < 4096; idx += 256) {
    int k = idx >> 7, g = idx & 127;
    dwT[idx] = dWih[g * 32 + k] + dWhh[g * 32 + k];  // din==dh every step
    qhhT[idx] = qWhh[g * 32 + k];
    rhhT[idx] = rWhh[g * 32 + k];
  }
  for (int idx = tid; idx < 3072; idx += 256) {
    int k = idx >> 7, g = idx & 127;
    qihT[idx] = qWih[g * 24 + k];
    rihT[idx] = rWih[g * 24 + k];
  }
  for (int idx = tid; idx < 384; idx += 256) {
    int k = idx / 12, j = idx - k * 12;
    owT[idx] = ow[j * 32 + k];
  }
  for (int idx = tid; idx < 768; idx += 256) {
    int k = idx / 24, j = idx - k * 24;
    qfwT[idx] = qfw[j * 32 + k];
    rfwT[idx] = rfw[j * 32 + k];
  }
  for (int idx = tid; idx < 128; idx += 256) {
    dbs[idx] = dbih[idx] + dbhh[idx];
    qbs[idx] = qbih[idx] + qbhh[idx];
    rbs[idx] = rbih[idx] + rbhh[idx];
  }
  __syncthreads();
  int lane = tid & 63, w = tid >> 6, b = blockIdx.x * 4 + w;
  float* tL = tL4 + w * 120;
  int xl = (lane & 31) + 32;
  int l12 = lane < 12 ? lane : 0;
  int l24 = lane < 24 ? lane : 0;
  float cc = 0.f, hh = 0.f;
  if (lane < 32) {
    hh = dh0[b * 32 + lane];
    cc = dc0[b * 32 + lane];
  }
  float aReg[5];
  // decoder: 5 steps
#pragma unroll 1
  for (int s = 0; s < 5; ++s) {
    float ga = dbs[lane], gb2 = dbs[lane + 64];
#pragma unroll
    for (int k = 0; k < 32; ++k) {
      float hk = __shfl(hh, k);
      ga += hk * dwT[k * 128 + lane];
      gb2 += hk * dwT[k * 128 + lane + 64];
    }
    float gaX = __shfl(ga, xl);
    float gbX = __shfl(gb2, xl);
    if (lane < 32) {
      float ig = sigf(ga), fg = sigf(gaX);
      float gg = tanhf2(gb2), og = sigf(gbX);
      cc = fg * cc + ig * gg;
      hh = og * tanhf2(cc);
    }
    float pa = ob[l12];
#pragma unroll
    for (int k = 0; k < 32; ++k) pa += __shfl(hh, k) * owT[k * 12 + l12];
    aReg[s] = pa;
  }
  // physics integration -> tL (traj)
  if (lane < 12) {
    int n = lane >> 1, d = lane & 1;
    float v0 = 0.f, p0 = 0.f;
    if (n == 0) {
      p0 = obs[(size_t)b * 40000 + 39600 + d];
      v0 = obs[(size_t)b * 40000 + 39600 + 2 + d];
    }
    float vc = v0, pc = p0;
#pragma unroll
    for (int s = 0; s < 5; ++s) {
      float a = aReg[s];
      vc += 0.1f * a;
      pc += vc * 0.1f + a * 0.005f;
      tL[s * 24 + n * 4 + d] = pc;
      tL[s * 24 + n * 4 + 2 + d] = vc;
    }
  }
  __syncthreads();
#pragma unroll
  for (int e = 0; e < 2; ++e) {
    int idx = lane + 64 * e;
    if (idx < 120) traj[(size_t)b * 120 + idx] = tL[idx];
  }
  // Q then R LSTM over traj
#pragma unroll 1
  for (int qr = 0; qr < 2; ++qr) {
    const float* ihT = qr ? rihT : qihT;
    const float* hhT = qr ? rhhT : qhhT;
    const float* bs = qr ? rbs : qbs;
    const float* fwT = qr ? rfwT : qfwT;
    const float* fbg = qr ? rfb : qfb;
    float* outg = qr ? rdg : qdg;
    hh = 0.f;
    cc = 0.f;
#pragma unroll 1
    for (int s = 0; s < 5; ++s) {
      float ga = bs[lane], gb2 = bs[lane + 64];
#pragma unroll
      for (int k = 0; k < 24; ++k) {
        float z = tL[s * 24 + k];
        ga += z * ihT[k * 128 + lane];
        gb2 += z * ihT[k * 128 + lane + 64];
      }
#pragma unroll
      for (int k = 0; k < 32; ++k) {
        float hk = __shfl(hh, k);
        ga += hk * hhT[k * 128 + lane];
        gb2 += hk * hhT[k * 128 + lane + 64];
      }
      float gaX = __shfl(ga, xl);
      float gbX = __shfl(gb2, xl);
      if (lane < 32) {
        float ig = sigf(ga), fg = sigf(gaX);
        float gg = tanhf2(gb2), og = sigf(gbX);
        cc = fg * cc + ig * gg;
        hh = og * tanhf2(cc);
      }
    }
    float qv = fbg[l24];
#pragma unroll
    for (int k = 0; k < 32; ++k) qv += __shfl(hh, k) * fwT[k * 24 + l24];
    if (lane < 24) outg[b * 24 + lane] = fabsf(qv);
  }
}

// ================= K6: Kalman filter, register-resident, one wave/batch ===
// Column-per-lane layout: lane j<24 holds P column j; aug matrix [S | Pm]
// columns on lanes 0..47. All cross-lane via __shfl; no LDS, no barriers.
// Uses S = Pm + diag(R) symmetric => solve(S,Pm^T) = S^{-1} Pm.
__global__ __launch_bounds__(64, 1)
void k6_kf(const float* __restrict__ obs, const float* __restrict__ traj,
           const float* __restrict__ qd, const float* __restrict__ rd,
           float* __restrict__ out) {
  int lane = threadIdx.x;
  int b = blockIdx.x;
  int l24 = (lane < 24) ? lane : 0;
  float sv = 0.f, qv = 0.f, rv = 0.f;
  if (lane < 24) {
    sv = (lane < 4) ? obs[(size_t)b * 40000 + 39600 + lane] : 0.f;
    qv = qd[b * 24 + lane];
    rv = rd[b * 24 + lane];
  }
  float p[24];
#pragma unroll
  for (int i = 0; i < 24; ++i) p[i] = (i == lane) ? 1.f : 0.f;
  const int srcPF = ((lane & 3) < 2) ? (lane + 2) : lane;  // in-range for all 64 lanes
  const int srcA = (lane < 24) ? lane : (lane - 24);
#pragma unroll 1
  for (int s = 0; s < 5; ++s) {
    // ---- s_m = F s ----
    float sshift = __shfl(sv, srcPF);
    float smv = sv + (((lane & 3) < 2) ? 0.1f * sshift : 0.f);
    // ---- P <- F P (row update, lane-local) ----
#pragma unroll
    for (int i = 0; i < 24; ++i)
      if ((i & 3) < 2) p[i] += 0.1f * p[i + 2];
    // ---- P <- P F^T (column update via shfl from col j+2) ----
#pragma unroll
    for (int i = 0; i < 24; ++i) {
      float t = __shfl(p[i], srcPF);
      if ((lane & 3) < 2) p[i] += 0.1f * t;
    }
    // ---- + Qm (diagonal) ----
#pragma unroll
    for (int i = 0; i < 24; ++i) p[i] += (i == lane) ? qv : 0.f;
    // ---- build aug [S | Pm]: lanes<24 S col, lanes 24..47 Pm col ----
    float a[24];
#pragma unroll
    for (int i = 0; i < 24; ++i) {
      float t = __shfl(p[i], srcA);
      a[i] = (lane < 24) ? (p[i] + ((i == lane) ? rv : 0.f)) : t;
    }
    // ---- Gauss-Jordan, no pivoting (S SPD) ----
#pragma unroll
    for (int k = 0; k < 24; ++k) {
      float piv = __shfl(a[k], k);
      float inv = 1.f / piv;
      float t = a[k] * inv;   // new row-k element in this column
#pragma unroll
      for (int i = 0; i < 24; ++i) {
        if (i != k) {
          float fi = __shfl(a[i], k);  // old ag[i][k] (lane k not yet updated)
          a[i] = fmaf(-fi, t, a[i]);
        }
      }
      a[k] = t;
    }
    // lanes 24+j now hold X = S^{-1} Pm column j;  K = X^T
    // ---- innovation & state update ----
    float zv = traj[(size_t)b * 120 + s * 24 + l24];
    float innv = zv - smv;  // valid on lanes<24 (shfl sources)
    float acc = 0.f;
#pragma unroll
    for (int m = 0; m < 24; ++m) acc += a[m] * __shfl(innv, m);
    float kupd = __shfl(acc, 24 + l24);  // lane i<24 pulls from lane 24+i
    sv = smv + kupd;
    if (lane < 24) out[(size_t)b * 120 + s * 24 + lane] = sv;
    // ---- P_new = Pm - X^T Pm : pn[i] = p[i] - sum_k X[k][i]*p[k] ----
    float pn[24];
#pragma unroll
    for (int i = 0; i < 24; ++i) {
      float acc2 = 0.f;
#pragma unroll
      for (int k = 0; k < 24; ++k) acc2 += __shfl(a[k], 24 + i) * p[k];
      pn[i] = p[i] - acc2;
    }
#pragma unroll
    for (int i = 0; i < 24; ++i) p[i] = pn[i];
  }
}

// =========================================================================
extern "C" void kernel_launch(void* const* d_in, const int* in_sizes, int n_in,
                              void* d_out, int out_size, void* d_ws, size_t ws_size,
                              hipStream_t stream) {
  (void)in_sizes; (void)n_in; (void)out_size; (void)ws_size;
  const float* obs  = (const float*)d_in[0];
  const float* c1w  = (const float*)d_in[1];
  const float* c1b  = (const float*)d_in[2];
  const float* c2w  = (const float*)d_in[3];
  const float* c2b  = (const float*)d_in[4];
  const float* f1w  = (const float*)d_in[5];
  const float* f1b  = (const float*)d_in[6];
  const float* bn1g = (const float*)d_in[7];
  const float* bn1b = (const float*)d_in[8];
  const float* f2w  = (const float*)d_in[9];
  const float* f2b  = (const float*)d_in[10];
  const float* bn2g = (const float*)d_in[11];
  const float* bn2b = (const float*)d_in[12];
  const float* eWih = (const float*)d_in[13];
  const float* eWhh = (const float*)d_in[14];
  const float* ebih = (const float*)d_in[15];
  const float* ebhh = (const float*)d_in[16];
  const float* dWih = (const float*)d_in[17];
  const float* dWhh = (const float*)d_in[18];
  const float* dbih = (const float*)d_in[19];
  const float* dbhh = (const float*)d_in[20];
  const float* ow   = (const float*)d_in[21];
  const float* ob   = (const float*)d_in[22];
  const float* qWih = (const float*)d_in[23];
  const float* qWhh = (const float*)d_in[24];
  const float* qbih = (const float*)d_in[25];
  const float* qbhh = (const float*)d_in[26];
  const float* qfw  = (const float*)d_in[27];
  const float* qfb  = (const float*)d_in[28];
  const float* rWih = (const float*)d_in[29];
  const float* rWhh = (const float*)d_in[30];
  const float* rbih = (const float*)d_in[31];
  const float* rbhh = (const float*)d_in[32];
  const float* rfw  = (const float*)d_in[33];
  const float* rfb  = (const float*)d_in[34];

  float* ws = (float*)d_ws;
  float* p1   = ws + P1_OFF;
  float* x    = ws + X_OFF;
  float* gx   = ws + GX_OFF;       // reuses p1 region (dead after k2)
  float* dh   = ws + SM_OFF;
  float* dc   = dh + 16384;
  float* traj = dh + 32768;
  float* qdg  = dh + 94208;
  float* rdg  = dh + 106496;
  float* out  = (float*)d_out;

  k1_conv1<<<1600, 256, 0, stream>>>(obs, c1w, c1b, p1);
  k2_conv2<<<dim3(200, 4), 256, 0, stream>>>(p1, c2w, c2b, x);
  k3_fc<<<800, 256, 0, stream>>>(x, f1w, f1b, bn1g, bn1b, f2w, f2b, bn2g, bn2b,
                                 eWih, ebih, ebhh, gx);
  k4_enc<<<512, 64, 0, stream>>>(gx, eWhh, dh, dc);
  k5_dec<<<128, 256, 0, stream>>>(obs, dWih, dWhh, dbih, dbhh, ow, ob,
                                  qWih, qWhh, qbih, qbhh, qfw, qfb,
                                  rWih, rWhh, rbih, rbhh, rfw, rfb,
                                  dh, dc, traj, qdg, rdg);
  k6_kf<<<512, 64, 0, stream>>>(obs, traj, qdg, rdg, out);
}

// Round 3
// 768.427 us; speedup vs baseline: 1.0585x; 1.0585x over previous
//
#include <hip/hip_runtime.h>

#define BT 51200      // B*T
#define NB 512        // batch

// ---------- workspace float offsets ----------
#define P1_OFF   ((size_t)0)
#define X_OFF    ((size_t)20480000)
#define GX_OFF   ((size_t)0)
#define SM_OFF   ((size_t)27033600)

__device__ __forceinline__ float sigf(float x) {
  return __fdividef(1.f, 1.f + __expf(-x));
}
__device__ __forceinline__ float tanhf2(float x) {
  float ax = fabsf(x);
  float e = __expf(-2.f * ax);
  float r = __fdividef(1.f - e, 1.f + e);
  return x < 0.f ? -r : r;
}

// ================= K1: conv1 (SAME 3x3, C=4->16) + relu + 2x2 maxpool =====
// Round-0 shape (64 items/block, full 400-float staging, 256B store
// segments -> WRITE_SIZE == ideal 80MB). New: software-pipelined c-loop
// (double row-buffer: load c+1 during FMAs of c) + weights hoisted out of
// the p-loop. LDS caps us at 1 block/CU (2 waves/SIMD) so VGPR up to 256
// is free -> buy latency hiding with ILP, not TLP.
__global__ __launch_bounds__(512, 1)
void k1_conv1(const float* __restrict__ obs, const float* __restrict__ w,
              const float* __restrict__ bias, float* __restrict__ p1) {
  __shared__ float xs[64 * 401];
  int tid = threadIdx.x;
  int i0 = blockIdx.x * 64;
  // stage 64 items x 400 floats, float4 loads, scalar LDS writes (stride 401)
  for (int idx = tid; idx < 6400; idx += 512) {
    int item = idx / 100, f = idx - item * 100;
    float4 v = ((const float4*)obs)[(size_t)(i0 + item) * 100 + f];
    float* d = xs + item * 401 + f * 4;
    d[0] = v.x; d[1] = v.y; d[2] = v.z; d[3] = v.w;
  }
  __syncthreads();
  int lane = tid & 63;
  int wv = tid >> 6;  // 0..7, wave-uniform -> out channels {2wv, 2wv+1}
  const float* xrow = xs + lane * 401;

  // hoist all weights for this thread's two output channels (static idx only)
  float wr[2][4][9];
#pragma unroll
  for (int u = 0; u < 2; ++u)
#pragma unroll
    for (int c = 0; c < 4; ++c)
#pragma unroll
      for (int t = 0; t < 9; ++t)
        wr[u][c][t] = w[(wv * 2 + u) * 36 + c * 9 + t];

#define K1_LOAD(R, C) do { \
  _Pragma("unroll") \
  for (int rr = 0; rr < 4; ++rr) { \
    int r = 2 * p - 1 + rr; \
    R[rr][0] = 0.f; R[rr][11] = 0.f; \
    if (r >= 0 && r <= 9) { \
      _Pragma("unroll") \
      for (int j = 0; j < 10; ++j) R[rr][j + 1] = xrow[(C) * 100 + r * 10 + j]; \
    } else { \
      _Pragma("unroll") \
      for (int j = 0; j < 10; ++j) R[rr][j + 1] = 0.f; \
    } \
  } } while (0)

#define K1_FMA(R, C) do { \
  _Pragma("unroll") \
  for (int u = 0; u < 2; ++u) { \
    _Pragma("unroll") \
    for (int q = 0; q < 5; ++q) \
      _Pragma("unroll") \
      for (int ii = 0; ii < 2; ++ii) \
        _Pragma("unroll") \
        for (int jj = 0; jj < 2; ++jj) { \
          float a = acc[u][q][ii][jj]; \
          int cb = 2 * q + jj; \
          a += R[ii][cb] * wr[u][C][0] + R[ii][cb + 1] * wr[u][C][1] + R[ii][cb + 2] * wr[u][C][2]; \
          a += R[ii + 1][cb] * wr[u][C][3] + R[ii + 1][cb + 1] * wr[u][C][4] + R[ii + 1][cb + 2] * wr[u][C][5]; \
          a += R[ii + 2][cb] * wr[u][C][6] + R[ii + 2][cb + 1] * wr[u][C][7] + R[ii + 2][cb + 2] * wr[u][C][8]; \
          acc[u][q][ii][jj] = a; \
        } \
  } } while (0)

#pragma unroll 1
  for (int p = 0; p < 5; ++p) {
    float acc[2][5][2][2];
#pragma unroll
    for (int u = 0; u < 2; ++u) {
      float bv = bias[wv * 2 + u];
#pragma unroll
      for (int q = 0; q < 5; ++q)
#pragma unroll
        for (int ii = 0; ii < 2; ++ii)
#pragma unroll
          for (int jj = 0; jj < 2; ++jj) acc[u][q][ii][jj] = bv;
    }
    float rowsA[4][12], rowsB[4][12];
    K1_LOAD(rowsA, 0);          // c=0 rows
    K1_LOAD(rowsB, 1);          // prefetch c=1
    K1_FMA(rowsA, 0);
    K1_LOAD(rowsA, 2);          // prefetch c=2
    K1_FMA(rowsB, 1);
    K1_LOAD(rowsB, 3);          // prefetch c=3
    K1_FMA(rowsA, 2);
    K1_FMA(rowsB, 3);
#pragma unroll
    for (int u = 0; u < 2; ++u) {
      int o = wv * 2 + u;
#pragma unroll
      for (int q = 0; q < 5; ++q) {
        float m = fmaxf(fmaxf(acc[u][q][0][0], acc[u][q][0][1]),
                        fmaxf(acc[u][q][1][0], acc[u][q][1][1]));
        m = fmaxf(m, 0.f);
        p1[(size_t)(o * 25 + p * 5 + q) * BT + i0 + lane] = m;
      }
    }
  }
#undef K1_LOAD
#undef K1_FMA
}

// ================= K2: conv2 (SAME 3x3, 16->32) + relu + 2x2 maxpool ======
__global__ __launch_bounds__(256, 2)
void k2_conv2(const float* __restrict__ p1, const float* __restrict__ w,
              const float* __restrict__ bias, float* __restrict__ x) {
  int item = blockIdx.x * 256 + threadIdx.x;
  int oc = blockIdx.y;
  float acc[8][16];
#pragma unroll
  for (int o = 0; o < 8; ++o) {
    float bv = bias[oc * 8 + o];
#pragma unroll
    for (int pos = 0; pos < 16; ++pos) acc[o][pos] = bv;
  }
#pragma unroll 1
  for (int c = 0; c < 16; ++c) {
    float in[6][6];
#pragma unroll
    for (int t = 0; t < 6; ++t) { in[0][t] = 0.f; in[t][0] = 0.f; }
#pragma unroll
    for (int i = 0; i < 5; ++i)
#pragma unroll
      for (int j = 0; j < 5; ++j)
        in[i + 1][j + 1] = p1[(size_t)(c * 25 + i * 5 + j) * BT + item];
#pragma unroll
    for (int o = 0; o < 8; ++o) {
#pragma unroll
      for (int i = 0; i < 4; ++i)
#pragma unroll
        for (int j = 0; j < 4; ++j) {
          float a = acc[o][i * 4 + j];
#pragma unroll
          for (int dr = 0; dr < 3; ++dr)
#pragma unroll
            for (int dj = 0; dj < 3; ++dj)
              a += in[i + dr][j + dj] * w[((oc * 8 + o) * 16 + c) * 9 + dr * 3 + dj];
          acc[o][i * 4 + j] = a;
        }
    }
  }
#pragma unroll
  for (int o = 0; o < 8; ++o)
#pragma unroll
    for (int p = 0; p < 2; ++p)
#pragma unroll
      for (int q = 0; q < 2; ++q) {
        float m = fmaxf(fmaxf(acc[o][(2 * p) * 4 + 2 * q], acc[o][(2 * p) * 4 + 2 * q + 1]),
                        fmaxf(acc[o][(2 * p + 1) * 4 + 2 * q], acc[o][(2 * p + 1) * 4 + 2 * q + 1]));
        m = fmaxf(m, 0.f);
        x[(size_t)((oc * 8 + o) * 4 + p * 2 + q) * BT + item] = m;
      }
}

// ================= K3: fc1(+bn,relu) -> fc2(+bn,relu) -> eWih projection ===
__global__ __launch_bounds__(256, 2)
void k3_fc(const float* __restrict__ x,
           const float* __restrict__ f1w, const float* __restrict__ f1b,
           const float* __restrict__ bn1g, const float* __restrict__ bn1b,
           const float* __restrict__ f2w, const float* __restrict__ f2b,
           const float* __restrict__ bn2g, const float* __restrict__ bn2b,
           const float* __restrict__ eWih, const float* __restrict__ ebih,
           const float* __restrict__ ebhh, float* __restrict__ gx) {
  __shared__ float xs[128 * 64];
  __shared__ float ys[128 * 64];
  const float BNRS = 0.9999950000374997f;  // 1/sqrt(1+1e-5)
  int tid = threadIdx.x;
  int lane = tid & 63;
  int wv = __builtin_amdgcn_readfirstlane(tid >> 6);
  int i0 = blockIdx.x * 64;
#pragma unroll
  for (int r = 0; r < 32; ++r) {
    int k = r * 4 + (tid >> 6);
    xs[k * 64 + lane] = x[(size_t)k * BT + i0 + lane];
  }
  __syncthreads();
#pragma unroll 1
  for (int jj = 0; jj < 8; ++jj) {
    int j0 = wv * 32 + jj * 4;
    float a[4] = {0.f, 0.f, 0.f, 0.f};
#pragma unroll 8
    for (int k = 0; k < 128; ++k) {
      float xv = xs[k * 64 + lane];
#pragma unroll
      for (int u = 0; u < 4; ++u) a[u] += xv * f1w[(j0 + u) * 128 + k];
    }
#pragma unroll
    for (int u = 0; u < 4; ++u) {
      int j = j0 + u;
      float v = a[u] + f1b[j];
      v = bn1g[j] * v * BNRS + bn1b[j];
      ys[j * 64 + lane] = fmaxf(v, 0.f);
    }
  }
  __syncthreads();
#pragma unroll 1
  for (int jj = 0; jj < 4; ++jj) {
    int j0 = wv * 16 + jj * 4;
    float a[4] = {0.f, 0.f, 0.f, 0.f};
#pragma unroll 8
    for (int k = 0; k < 128; ++k) {
      float yv = ys[k * 64 + lane];
#pragma unroll
      for (int u = 0; u < 4; ++u) a[u] += yv * f2w[(j0 + u) * 128 + k];
    }
#pragma unroll
    for (int u = 0; u < 4; ++u) {
      int j = j0 + u;
      float v = a[u] + f2b[j];
      v = bn2g[j] * v * BNRS + bn2b[j];
      xs[j * 64 + lane] = fmaxf(v, 0.f);
    }
  }
  __syncthreads();
#pragma unroll 1
  for (int jj = 0; jj < 8; ++jj) {
    int j0 = wv * 32 + jj * 4;
    float a[4] = {0.f, 0.f, 0.f, 0.f};
#pragma unroll 8
    for (int k = 0; k < 64; ++k) {
      float zv = xs[k * 64 + lane];
#pragma unroll
      for (int u = 0; u < 4; ++u) a[u] += zv * eWih[(j0 + u) * 64 + k];
    }
#pragma unroll
    for (int u = 0; u < 4; ++u) {
      int j = j0 + u;
      gx[(size_t)j * BT + i0 + lane] = a[u] + ebih[j] + ebhh[j];
    }
  }
}

// ================= K4: encoder LSTM (T=100), one wave per batch ===========
__global__ __launch_bounds__(64, 4)
void k4_enc(const float* __restrict__ gx, const float* __restrict__ eWhh,
            float* __restrict__ dh, float* __restrict__ dc) {
  __shared__ float wT[32 * 128];  // [k][gate]
  int lane = threadIdx.x;
  int b = blockIdx.x;
#pragma unroll 1
  for (int r = 0; r < 64; ++r) {
    int idx = lane + r * 64;
    int g = idx & 127, k = idx >> 7;
    wT[k * 128 + g] = eWhh[g * 32 + k];
  }
  __syncthreads();
  float c = 0.f, h = 0.f;
  size_t base0 = (size_t)b * 100;
  float ga_n = gx[(size_t)lane * BT + base0];
  float gb_n = gx[(size_t)(lane + 64) * BT + base0];
  int xl = (lane & 31) + 32;
#pragma unroll 1
  for (int t = 0; t < 100; ++t) {
    float ga = ga_n, gb2 = gb_n;
    if (t < 99) {
      ga_n = gx[(size_t)lane * BT + base0 + t + 1];
      gb_n = gx[(size_t)(lane + 64) * BT + base0 + t + 1];
    }
#pragma unroll
    for (int k = 0; k < 32; ++k) {
      float hk = __shfl(h, k);
      ga += hk * wT[k * 128 + lane];
      gb2 += hk * wT[k * 128 + lane + 64];
    }
    float gaX = __shfl(ga, xl);   // gate lane+32 (f for lanes<32)
    float gbX = __shfl(gb2, xl);  // gate lane+96 (o for lanes<32)
    if (lane < 32) {
      float ig = sigf(ga);
      float fg = sigf(gaX);
      float gg = tanhf2(gb2);
      float og = sigf(gbX);
      c = fg * c + ig * gg;
      h = og * tanhf2(c);
    }
  }
  if (lane < 32) {
    dh[b * 32 + lane] = h;
    dc[b * 32 + lane] = c;
  }
}

// ====== K5: decoder LSTM (din==dh identity) + physics + Q/R LSTMs =========
__global__ __launch_bounds__(256, 2)
void k5_dec(const float* __restrict__ obs,
            const float* __restrict__ dWih, const float* __restrict__ dWhh,
            const float* __restrict__ dbih, const float* __restrict__ dbhh,
            const float* __restrict__ ow, const float* __restrict__ ob,
            const float* __restrict__ qWih, const float* __restrict__ qWhh,
            const float* __restrict__ qbih, const float* __restrict__ qbhh,
            const float* __restrict__ qfw, const float* __restrict__ qfb,
            const float* __restrict__ rWih, const float* __restrict__ rWhh,
            const float* __restrict__ rbih, const float* __restrict__ rbhh,
            const float* __restrict__ rfw, const float* __restrict__ rfb,
            const float* __restrict__ dh0, const float* __restrict__ dc0,
            float* __restrict__ traj, float* __restrict__ qdg, float* __restrict__ rdg) {
  __shared__ float dwT[32 * 128], qihT[24 * 128], qhhT[32 * 128], rihT[24 * 128], rhhT[32 * 128];
  __shared__ float owT[32 * 12], qfwT[32 * 24], rfwT[32 * 24];
  __shared__ float dbs[128], qbs[128], rbs[128];
  __shared__ float tL4[4 * 120];
  int tid = threadIdx.x;
  for (int idx = tid; idx < 4096; idx += 256) {
    int k = idx >> 7, g = idx & 127;
    dwT[idx] = dWih[g * 32 + k] + dWhh[g * 32 + k];  // din==dh every step
    qhhT[idx] = qWhh[g * 32 + k];
    rhhT[idx] = rWhh[g * 32 + k];
  }
  for (int idx = tid; idx < 3072; idx += 256) {
    int k = idx >> 7, g = idx & 127;
    qihT[idx] = qWih[g * 24 + k];
    rihT[idx] = rWih[g * 24 + k];
  }
  for (int idx = tid; idx < 384; idx += 256) {
    int k = idx / 12, j = idx - k * 12;
    owT[idx] = ow[j * 32 + k];
  }
  for (int idx = tid; idx < 768; idx += 256) {
    int k = idx / 24, j = idx - k * 24;
    qfwT[idx] = qfw[j * 32 + k];
    rfwT[idx] = rfw[j * 32 + k];
  }
  for (int idx = tid; idx < 128; idx += 256) {
    dbs[idx] = dbih[idx] + dbhh[idx];
    qbs[idx] = qbih[idx] + qbhh[idx];
    rbs[idx] = rbih[idx] + rbhh[idx];
  }
  __syncthreads();
  int lane = tid & 63, w = tid >> 6, b = blockIdx.x * 4 + w;
  float* tL = tL4 + w * 120;
  int xl = (lane & 31) + 32;
  int l12 = lane < 12 ? lane : 0;
  int l24 = lane < 24 ? lane : 0;
  float cc = 0.f, hh = 0.f;
  if (lane < 32) {
    hh = dh0[b * 32 + lane];
    cc = dc0[b * 32 + lane];
  }
  float aReg[5];
  // decoder: 5 steps
#pragma unroll 1
  for (int s = 0; s < 5; ++s) {
    float ga = dbs[lane], gb2 = dbs[lane + 64];
#pragma unroll
    for (int k = 0; k < 32; ++k) {
      float hk = __shfl(hh, k);
      ga += hk * dwT[k * 128 + lane];
      gb2 += hk * dwT[k * 128 + lane + 64];
    }
    float gaX = __shfl(ga, xl);
    float gbX = __shfl(gb2, xl);
    if (lane < 32) {
      float ig = sigf(ga), fg = sigf(gaX);
      float gg = tanhf2(gb2), og = sigf(gbX);
      cc = fg * cc + ig * gg;
      hh = og * tanhf2(cc);
    }
    float pa = ob[l12];
#pragma unroll
    for (int k = 0; k < 32; ++k) pa += __shfl(hh, k) * owT[k * 12 + l12];
    aReg[s] = pa;
  }
  // physics integration -> tL (traj)
  if (lane < 12) {
    int n = lane >> 1, d = lane & 1;
    float v0 = 0.f, p0 = 0.f;
    if (n == 0) {
      p0 = obs[(size_t)b * 40000 + 39600 + d];
      v0 = obs[(size_t)b * 40000 + 39600 + 2 + d];
    }
    float vc = v0, pc = p0;
#pragma unroll
    for (int s = 0; s < 5; ++s) {
      float a = aReg[s];
      vc += 0.1f * a;
      pc += vc * 0.1f + a * 0.005f;
      tL[s * 24 + n * 4 + d] = pc;
      tL[s * 24 + n * 4 + 2 + d] = vc;
    }
  }
  __syncthreads();
#pragma unroll
  for (int e = 0; e < 2; ++e) {
    int idx = lane + 64 * e;
    if (idx < 120) traj[(size_t)b * 120 + idx] = tL[idx];
  }
  // Q then R LSTM over traj
#pragma unroll 1
  for (int qr = 0; qr < 2; ++qr) {
    const float* ihT = qr ? rihT : qihT;
    const float* hhT = qr ? rhhT : qhhT;
    const float* bs = qr ? rbs : qbs;
    const float* fwT = qr ? rfwT : qfwT;
    const float* fbg = qr ? rfb : qfb;
    float* outg = qr ? rdg : qdg;
    hh = 0.f;
    cc = 0.f;
#pragma unroll 1
    for (int s = 0; s < 5; ++s) {
      float ga = bs[lane], gb2 = bs[lane + 64];
#pragma unroll
      for (int k = 0; k < 24; ++k) {
        float z = tL[s * 24 + k];
        ga += z * ihT[k * 128 + lane];
        gb2 += z * ihT[k * 128 + lane + 64];
      }
#pragma unroll
      for (int k = 0; k < 32; ++k) {
        float hk = __shfl(hh, k);
        ga += hk * hhT[k * 128 + lane];
        gb2 += hk * hhT[k * 128 + lane + 64];
      }
      float gaX = __shfl(ga, xl);
      float gbX = __shfl(gb2, xl);
      if (lane < 32) {
        float ig = sigf(ga), fg = sigf(gaX);
        float gg = tanhf2(gb2), og = sigf(gbX);
        cc = fg * cc + ig * gg;
        hh = og * tanhf2(cc);
      }
    }
    float qv = fbg[l24];
#pragma unroll
    for (int k = 0; k < 32; ++k) qv += __shfl(hh, k) * fwT[k * 24 + l24];
    if (lane < 24) outg[b * 24 + lane] = fabsf(qv);
  }
}

// ================= K6: Kalman filter, register-resident, one wave/batch ===
// Column-per-lane layout: lane j<24 holds P column j; aug matrix [S | Pm]
// columns on lanes 0..47. All cross-lane via __shfl; no LDS, no barriers.
// Uses S = Pm + diag(R) symmetric => solve(S,Pm^T) = S^{-1} Pm.
__global__ __launch_bounds__(64, 1)
void k6_kf(const float* __restrict__ obs, const float* __restrict__ traj,
           const float* __restrict__ qd, const float* __restrict__ rd,
           float* __restrict__ out) {
  int lane = threadIdx.x;
  int b = blockIdx.x;
  int l24 = (lane < 24) ? lane : 0;
  float sv = 0.f, qv = 0.f, rv = 0.f;
  if (lane < 24) {
    sv = (lane < 4) ? obs[(size_t)b * 40000 + 39600 + lane] : 0.f;
    qv = qd[b * 24 + lane];
    rv = rd[b * 24 + lane];
  }
  float p[24];
#pragma unroll
  for (int i = 0; i < 24; ++i) p[i] = (i == lane) ? 1.f : 0.f;
  const int srcPF = ((lane & 3) < 2) ? (lane + 2) : lane;  // in-range for all 64 lanes
  const int srcA = (lane < 24) ? lane : (lane - 24);
#pragma unroll 1
  for (int s = 0; s < 5; ++s) {
    // ---- s_m = F s ----
    float sshift = __shfl(sv, srcPF);
    float smv = sv + (((lane & 3) < 2) ? 0.1f * sshift : 0.f);
    // ---- P <- F P (row update, lane-local) ----
#pragma unroll
    for (int i = 0; i < 24; ++i)
      if ((i & 3) < 2) p[i] += 0.1f * p[i + 2];
    // ---- P <- P F^T (column update via shfl from col j+2) ----
#pragma unroll
    for (int i = 0; i < 24; ++i) {
      float t = __shfl(p[i], srcPF);
      if ((lane & 3) < 2) p[i] += 0.1f * t;
    }
    // ---- + Qm (diagonal) ----
#pragma unroll
    for (int i = 0; i < 24; ++i) p[i] += (i == lane) ? qv : 0.f;
    // ---- build aug [S | Pm]: lanes<24 S col, lanes 24..47 Pm col ----
    float a[24];
#pragma unroll
    for (int i = 0; i < 24; ++i) {
      float t = __shfl(p[i], srcA);
      a[i] = (lane < 24) ? (p[i] + ((i == lane) ? rv : 0.f)) : t;
    }
    // ---- Gauss-Jordan, no pivoting (S SPD) ----
#pragma unroll
    for (int k = 0; k < 24; ++k) {
      float piv = __shfl(a[k], k);
      float inv = 1.f / piv;
      float t = a[k] * inv;   // new row-k element in this column
#pragma unroll
      for (int i = 0; i < 24; ++i) {
        if (i != k) {
          float fi = __shfl(a[i], k);  // old ag[i][k] (lane k not yet updated)
          a[i] = fmaf(-fi, t, a[i]);
        }
      }
      a[k] = t;
    }
    // lanes 24+j now hold X = S^{-1} Pm column j;  K = X^T
    // ---- innovation & state update ----
    float zv = traj[(size_t)b * 120 + s * 24 + l24];
    float innv = zv - smv;  // valid on lanes<24 (shfl sources)
    float acc = 0.f;
#pragma unroll
    for (int m = 0; m < 24; ++m) acc += a[m] * __shfl(innv, m);
    float kupd = __shfl(acc, 24 + l24);  // lane i<24 pulls from lane 24+i
    sv = smv + kupd;
    if (lane < 24) out[(size_t)b * 120 + s * 24 + lane] = sv;
    // ---- P_new = Pm - X^T Pm : pn[i] = p[i] - sum_k X[k][i]*p[k] ----
    float pn[24];
#pragma unroll
    for (int i = 0; i < 24; ++i) {
      float acc2 = 0.f;
#pragma unroll
      for (int k = 0; k < 24; ++k) acc2 += __shfl(a[k], 24 + i) * p[k];
      pn[i] = p[i] - acc2;
    }
#pragma unroll
    for (int i = 0; i < 24; ++i) p[i] = pn[i];
  }
}

// =========================================================================
extern "C" void kernel_launch(void* const* d_in, const int* in_sizes, int n_in,
                              void* d_out, int out_size, void* d_ws, size_t ws_size,
                              hipStream_t stream) {
  (void)in_sizes; (void)n_in; (void)out_size; (void)ws_size;
  const float* obs  = (const float*)d_in[0];
  const float* c1w  = (const float*)d_in[1];
  const float* c1b  = (const float*)d_in[2];
  const float* c2w  = (const float*)d_in[3];
  const float* c2b  = (const float*)d_in[4];
  const float* f1w  = (const float*)d_in[5];
  const float* f1b  = (const float*)d_in[6];
  const float* bn1g = (const float*)d_in[7];
  const float* bn1b = (const float*)d_in[8];
  const float* f2w  = (const float*)d_in[9];
  const float* f2b  = (const float*)d_in[10];
  const float* bn2g = (const float*)d_in[11];
  const float* bn2b = (const float*)d_in[12];
  const float* eWih = (const float*)d_in[13];
  const float* eWhh = (const float*)d_in[14];
  const float* ebih = (const float*)d_in[15];
  const float* ebhh = (const float*)d_in[16];
  const float* dWih = (const float*)d_in[17];
  const float* dWhh = (const float*)d_in[18];
  const float* dbih = (const float*)d_in[19];
  const float* dbhh = (const float*)d_in[20];
  const float* ow   = (const float*)d_in[21];
  const float* ob   = (const float*)d_in[22];
  const float* qWih = (const float*)d_in[23];
  const float* qWhh = (const float*)d_in[24];
  const float* qbih = (const float*)d_in[25];
  const float* qbhh = (const float*)d_in[26];
  const float* qfw  = (const float*)d_in[27];
  const float* qfb  = (const float*)d_in[28];
  const float* rWih = (const float*)d_in[29];
  const float* rWhh = (const float*)d_in[30];
  const float* rbih = (const float*)d_in[31];
  const float* rbhh = (const float*)d_in[32];
  const float* rfw  = (const float*)d_in[33];
  const float* rfb  = (const float*)d_in[34];

  float* ws = (float*)d_ws;
  float* p1   = ws + P1_OFF;
  float* x    = ws + X_OFF;
  float* gx   = ws + GX_OFF;       // reuses p1 region (dead after k2)
  float* dh   = ws + SM_OFF;
  float* dc   = dh + 16384;
  float* traj = dh + 32768;
  float* qdg  = dh + 94208;
  float* rdg  = dh + 106496;
  float* out  = (float*)d_out;

  k1_conv1<<<800, 512, 0, stream>>>(obs, c1w, c1b, p1);
  k2_conv2<<<dim3(200, 4), 256, 0, stream>>>(p1, c2w, c2b, x);
  k3_fc<<<800, 256, 0, stream>>>(x, f1w, f1b, bn1g, bn1b, f2w, f2b, bn2g, bn2b,
                                 eWih, ebih, ebhh, gx);
  k4_enc<<<512, 64, 0, stream>>>(gx, eWhh, dh, dc);
  k5_dec<<<128, 256, 0, stream>>>(obs, dWih, dWhh, dbih, dbhh, ow, ob,
                                  qWih, qWhh, qbih, qbhh, qfw, qfb,
                                  rWih, rWhh, rbih, rbhh, rfw, rfb,
                                  dh, dc, traj, qdg, rdg);
  k6_kf<<<512, 64, 0, stream>>>(obs, traj, qdg, rdg, out);
}

// Round 4
// 732.656 us; speedup vs baseline: 1.1102x; 1.0488x over previous
//
#include <hip/hip_runtime.h>

#define BT 51200      // B*T
#define NB 512        // batch

// ---------- workspace float offsets ----------
#define P1_OFF   ((size_t)0)
#define X_OFF    ((size_t)20480000)
#define GX_OFF   ((size_t)0)
#define SM_OFF   ((size_t)27033600)

__device__ __forceinline__ float sigf(float x) {
  return __fdividef(1.f, 1.f + __expf(-x));
}
__device__ __forceinline__ float tanhf2(float x) {
  float ax = fabsf(x);
  float e = __expf(-2.f * ax);
  float r = __fdividef(1.f - e, 1.f + e);
  return x < 0.f ? -r : r;
}

// ================= K1: conv1 (SAME 3x3, C=4->16) + relu + 2x2 maxpool =====
// Round-0 memory shape (64 items/block, single staging, 256B store segments
// -> WRITE_SIZE == ideal 80MB). VGPR ledger: rounds 1-3 all spilled because
// live demand exceeded what the allocator gives (~128); spill traffic showed
// as 3-5x WRITE_SIZE. This version pipelines WITHIN 128 VGPRs:
//  - wv uniform via readfirstlane -> weights/bias go to SGPRs (s_load),
//    off the VGPR budget; FMA uses the 1-SGPR-operand slot.
//  - rolling 6x12-float row window (72 VGPR): the 16 rows per p stream
//    through R0..R5, each 2-row load issued one 180-FMA unit ahead of its
//    consumer -> LDS latency hidden; one 3-row stall per p (5/block vs 20).
// Peak live ~ 40 acc + 72 rows + ~10 addr = ~122 VGPR.
__global__ __launch_bounds__(512, 1)
void k1_conv1(const float* __restrict__ obs, const float* __restrict__ w,
              const float* __restrict__ bias, float* __restrict__ p1) {
  __shared__ float xs[64 * 401];
  int tid = threadIdx.x;
  int i0 = blockIdx.x * 64;
  // staging: identical to round 0 (measured: FETCH 40MB, 25600 conflicts)
  for (int idx = tid; idx < 25600; idx += 512) {
    int item = idx / 400, feat = idx - item * 400;
    xs[item * 401 + feat] = obs[(size_t)(i0 + item) * 400 + feat];
  }
  __syncthreads();
  int lane = tid & 63;
  int wv = __builtin_amdgcn_readfirstlane(tid >> 6);  // 0..7, wave-uniform
  const float* xrow = xs + lane * 401;

// load one padded input row (c=C, row index RR within the 4-row band) into R
#define LOADR(R, C, RR) do { \
  int r_ = 2 * p - 1 + (RR); \
  R[0] = 0.f; R[11] = 0.f; \
  if (r_ >= 0 && r_ <= 9) { \
    _Pragma("unroll") \
    for (int j = 0; j < 10; ++j) R[j + 1] = xrow[(C) * 100 + r_ * 10 + j]; \
  } else { \
    _Pragma("unroll") \
    for (int j = 0; j < 10; ++j) R[j + 1] = 0.f; \
  } \
} while (0)

// one FMA unit: output-row-pair II of channel C from rows RA,RB,RC (180 FMA)
// weights via uniform pointer -> s_load -> SGPR operand in v_fma
#define FMAU(II, RA, RB, RC, C) do { \
  const float* wa_ = w + (wv * 2) * 36 + (C) * 9; \
  const float* wb_ = wa_ + 36; \
  _Pragma("unroll") \
  for (int q = 0; q < 5; ++q) { \
    _Pragma("unroll") \
    for (int jj = 0; jj < 2; ++jj) { \
      int cb = 2 * q + jj; \
      acc[0][q][II][jj] += RA[cb] * wa_[0] + RA[cb + 1] * wa_[1] + RA[cb + 2] * wa_[2] \
                         + RB[cb] * wa_[3] + RB[cb + 1] * wa_[4] + RB[cb + 2] * wa_[5] \
                         + RC[cb] * wa_[6] + RC[cb + 1] * wa_[7] + RC[cb + 2] * wa_[8]; \
      acc[1][q][II][jj] += RA[cb] * wb_[0] + RA[cb + 1] * wb_[1] + RA[cb + 2] * wb_[2] \
                         + RB[cb] * wb_[3] + RB[cb + 1] * wb_[4] + RB[cb + 2] * wb_[5] \
                         + RC[cb] * wb_[6] + RC[cb + 1] * wb_[7] + RC[cb + 2] * wb_[8]; \
    } \
  } \
} while (0)

  float b0 = bias[wv * 2 + 0];
  float b1 = bias[wv * 2 + 1];

#pragma unroll 1
  for (int p = 0; p < 5; ++p) {
    float acc[2][5][2][2];
#pragma unroll
    for (int q = 0; q < 5; ++q)
#pragma unroll
      for (int ii = 0; ii < 2; ++ii)
#pragma unroll
        for (int jj = 0; jj < 2; ++jj) {
          acc[0][q][ii][jj] = b0;
          acc[1][q][ii][jj] = b1;
        }
    float R0[12], R1[12], R2[12], R3[12], R4[12], R5[12];
    // stream s0..s15 = (c0,r0..3)(c1,r0..3)(c2,r0..3)(c3,r0..3), buf = s%6
    LOADR(R0, 0, 0); LOADR(R1, 0, 1); LOADR(R2, 0, 2);  // s0,s1,s2
    LOADR(R3, 0, 3); LOADR(R4, 1, 0);                   // s3,s4
    FMAU(0, R0, R1, R2, 0);                             // U0
    LOADR(R5, 1, 1); LOADR(R0, 1, 2);                   // s5,s6
    FMAU(1, R1, R2, R3, 0);                             // U1
    LOADR(R1, 1, 3); LOADR(R2, 2, 0);                   // s7,s8
    FMAU(0, R4, R5, R0, 1);                             // U2
    LOADR(R3, 2, 1); LOADR(R4, 2, 2);                   // s9,s10
    FMAU(1, R5, R0, R1, 1);                             // U3
    LOADR(R5, 2, 3); LOADR(R0, 3, 0);                   // s11,s12
    FMAU(0, R2, R3, R4, 2);                             // U4
    LOADR(R1, 3, 1); LOADR(R2, 3, 2);                   // s13,s14
    FMAU(1, R3, R4, R5, 2);                             // U5
    LOADR(R3, 3, 3);                                    // s15
    FMAU(0, R0, R1, R2, 3);                             // U6
    FMAU(1, R1, R2, R3, 3);                             // U7
    // 2x2 maxpool + relu + store (round-0 pattern, 256B segments)
#pragma unroll
    for (int u = 0; u < 2; ++u) {
      int o = wv * 2 + u;
#pragma unroll
      for (int q = 0; q < 5; ++q) {
        float m = fmaxf(fmaxf(acc[u][q][0][0], acc[u][q][0][1]),
                        fmaxf(acc[u][q][1][0], acc[u][q][1][1]));
        m = fmaxf(m, 0.f);
        p1[(size_t)(o * 25 + p * 5 + q) * BT + i0 + lane] = m;
      }
    }
  }
#undef LOADR
#undef FMAU
}

// ================= K2: conv2 (SAME 3x3, 16->32) + relu + 2x2 maxpool ======
__global__ __launch_bounds__(256, 2)
void k2_conv2(const float* __restrict__ p1, const float* __restrict__ w,
              const float* __restrict__ bias, float* __restrict__ x) {
  int item = blockIdx.x * 256 + threadIdx.x;
  int oc = blockIdx.y;
  float acc[8][16];
#pragma unroll
  for (int o = 0; o < 8; ++o) {
    float bv = bias[oc * 8 + o];
#pragma unroll
    for (int pos = 0; pos < 16; ++pos) acc[o][pos] = bv;
  }
#pragma unroll 1
  for (int c = 0; c < 16; ++c) {
    float in[6][6];
#pragma unroll
    for (int t = 0; t < 6; ++t) { in[0][t] = 0.f; in[t][0] = 0.f; }
#pragma unroll
    for (int i = 0; i < 5; ++i)
#pragma unroll
      for (int j = 0; j < 5; ++j)
        in[i + 1][j + 1] = p1[(size_t)(c * 25 + i * 5 + j) * BT + item];
#pragma unroll
    for (int o = 0; o < 8; ++o) {
#pragma unroll
      for (int i = 0; i < 4; ++i)
#pragma unroll
        for (int j = 0; j < 4; ++j) {
          float a = acc[o][i * 4 + j];
#pragma unroll
          for (int dr = 0; dr < 3; ++dr)
#pragma unroll
            for (int dj = 0; dj < 3; ++dj)
              a += in[i + dr][j + dj] * w[((oc * 8 + o) * 16 + c) * 9 + dr * 3 + dj];
          acc[o][i * 4 + j] = a;
        }
    }
  }
#pragma unroll
  for (int o = 0; o < 8; ++o)
#pragma unroll
    for (int p = 0; p < 2; ++p)
#pragma unroll
      for (int q = 0; q < 2; ++q) {
        float m = fmaxf(fmaxf(acc[o][(2 * p) * 4 + 2 * q], acc[o][(2 * p) * 4 + 2 * q + 1]),
                        fmaxf(acc[o][(2 * p + 1) * 4 + 2 * q], acc[o][(2 * p + 1) * 4 + 2 * q + 1]));
        m = fmaxf(m, 0.f);
        x[(size_t)((oc * 8 + o) * 4 + p * 2 + q) * BT + item] = m;
      }
}

// ================= K3: fc1(+bn,relu) -> fc2(+bn,relu) -> eWih projection ===
__global__ __launch_bounds__(256, 2)
void k3_fc(const float* __restrict__ x,
           const float* __restrict__ f1w, const float* __restrict__ f1b,
           const float* __restrict__ bn1g, const float* __restrict__ bn1b,
           const float* __restrict__ f2w, const float* __restrict__ f2b,
           const float* __restrict__ bn2g, const float* __restrict__ bn2b,
           const float* __restrict__ eWih, const float* __restrict__ ebih,
           const float* __restrict__ ebhh, float* __restrict__ gx) {
  __shared__ float xs[128 * 64];
  __shared__ float ys[128 * 64];
  const float BNRS = 0.9999950000374997f;  // 1/sqrt(1+1e-5)
  int tid = threadIdx.x;
  int lane = tid & 63;
  int wv = __builtin_amdgcn_readfirstlane(tid >> 6);
  int i0 = blockIdx.x * 64;
#pragma unroll
  for (int r = 0; r < 32; ++r) {
    int k = r * 4 + (tid >> 6);
    xs[k * 64 + lane] = x[(size_t)k * BT + i0 + lane];
  }
  __syncthreads();
#pragma unroll 1
  for (int jj = 0; jj < 8; ++jj) {
    int j0 = wv * 32 + jj * 4;
    float a[4] = {0.f, 0.f, 0.f, 0.f};
#pragma unroll 8
    for (int k = 0; k < 128; ++k) {
      float xv = xs[k * 64 + lane];
#pragma unroll
      for (int u = 0; u < 4; ++u) a[u] += xv * f1w[(j0 + u) * 128 + k];
    }
#pragma unroll
    for (int u = 0; u < 4; ++u) {
      int j = j0 + u;
      float v = a[u] + f1b[j];
      v = bn1g[j] * v * BNRS + bn1b[j];
      ys[j * 64 + lane] = fmaxf(v, 0.f);
    }
  }
  __syncthreads();
#pragma unroll 1
  for (int jj = 0; jj < 4; ++jj) {
    int j0 = wv * 16 + jj * 4;
    float a[4] = {0.f, 0.f, 0.f, 0.f};
#pragma unroll 8
    for (int k = 0; k < 128; ++k) {
      float yv = ys[k * 64 + lane];
#pragma unroll
      for (int u = 0; u < 4; ++u) a[u] += yv * f2w[(j0 + u) * 128 + k];
    }
#pragma unroll
    for (int u = 0; u < 4; ++u) {
      int j = j0 + u;
      float v = a[u] + f2b[j];
      v = bn2g[j] * v * BNRS + bn2b[j];
      xs[j * 64 + lane] = fmaxf(v, 0.f);
    }
  }
  __syncthreads();
#pragma unroll 1
  for (int jj = 0; jj < 8; ++jj) {
    int j0 = wv * 32 + jj * 4;
    float a[4] = {0.f, 0.f, 0.f, 0.f};
#pragma unroll 8
    for (int k = 0; k < 64; ++k) {
      float zv = xs[k * 64 + lane];
#pragma unroll
      for (int u = 0; u < 4; ++u) a[u] += zv * eWih[(j0 + u) * 64 + k];
    }
#pragma unroll
    for (int u = 0; u < 4; ++u) {
      int j = j0 + u;
      gx[(size_t)j * BT + i0 + lane] = a[u] + ebih[j] + ebhh[j];
    }
  }
}

// ================= K4: encoder LSTM (T=100), one wave per batch ===========
__global__ __launch_bounds__(64, 4)
void k4_enc(const float* __restrict__ gx, const float* __restrict__ eWhh,
            float* __restrict__ dh, float* __restrict__ dc) {
  __shared__ float wT[32 * 128];  // [k][gate]
  int lane = threadIdx.x;
  int b = blockIdx.x;
#pragma unroll 1
  for (int r = 0; r < 64; ++r) {
    int idx = lane + r * 64;
    int g = idx & 127, k = idx >> 7;
    wT[k * 128 + g] = eWhh[g * 32 + k];
  }
  __syncthreads();
  float c = 0.f, h = 0.f;
  size_t base0 = (size_t)b * 100;
  float ga_n = gx[(size_t)lane * BT + base0];
  float gb_n = gx[(size_t)(lane + 64) * BT + base0];
  int xl = (lane & 31) + 32;
#pragma unroll 1
  for (int t = 0; t < 100; ++t) {
    float ga = ga_n, gb2 = gb_n;
    if (t < 99) {
      ga_n = gx[(size_t)lane * BT + base0 + t + 1];
      gb_n = gx[(size_t)(lane + 64) * BT + base0 + t + 1];
    }
#pragma unroll
    for (int k = 0; k < 32; ++k) {
      float hk = __shfl(h, k);
      ga += hk * wT[k * 128 + lane];
      gb2 += hk * wT[k * 128 + lane + 64];
    }
    float gaX = __shfl(ga, xl);   // gate lane+32 (f for lanes<32)
    float gbX = __shfl(gb2, xl);  // gate lane+96 (o for lanes<32)
    if (lane < 32) {
      float ig = sigf(ga);
      float fg = sigf(gaX);
      float gg = tanhf2(gb2);
      float og = sigf(gbX);
      c = fg * c + ig * gg;
      h = og * tanhf2(c);
    }
  }
  if (lane < 32) {
    dh[b * 32 + lane] = h;
    dc[b * 32 + lane] = c;
  }
}

// ====== K5: decoder LSTM (din==dh identity) + physics + Q/R LSTMs =========
__global__ __launch_bounds__(256, 2)
void k5_dec(const float* __restrict__ obs,
            const float* __restrict__ dWih, const float* __restrict__ dWhh,
            const float* __restrict__ dbih, const float* __restrict__ dbhh,
            const float* __restrict__ ow, const float* __restrict__ ob,
            const float* __restrict__ qWih, const float* __restrict__ qWhh,
            const float* __restrict__ qbih, const float* __restrict__ qbhh,
            const float* __restrict__ qfw, const float* __restrict__ qfb,
            const float* __restrict__ rWih, const float* __restrict__ rWhh,
            const float* __restrict__ rbih, const float* __restrict__ rbhh,
            const float* __restrict__ rfw, const float* __restrict__ rfb,
            const float* __restrict__ dh0, const float* __restrict__ dc0,
            float* __restrict__ traj, float* __restrict__ qdg, float* __restrict__ rdg) {
  __shared__ float dwT[32 * 128], qihT[24 * 128], qhhT[32 * 128], rihT[24 * 128], rhhT[32 * 128];
  __shared__ float owT[32 * 12], qfwT[32 * 24], rfwT[32 * 24];
  __shared__ float dbs[128], qbs[128], rbs[128];
  __shared__ float tL4[4 * 120];
  int tid = threadIdx.x;
  for (int idx = tid; idx < 4096; idx += 256) {
    int k = idx >> 7, g = idx & 127;
    dwT[idx] = dWih[g * 32 + k] + dWhh[g * 32 + k];  // din==dh every step
    qhhT[idx] = qWhh[g * 32 + k];
    rhhT[idx] = rWhh[g * 32 + k];
  }
  for (int idx = tid; idx < 3072; idx += 256) {
    int k = idx >> 7, g = idx & 127;
    qihT[idx] = qWih[g * 24 + k];
    rihT[idx] = rWih[g * 24 + k];
  }
  for (int idx = tid; idx < 384; idx += 256) {
    int k = idx / 12, j = idx - k * 12;
    owT[idx] = ow[j * 32 + k];
  }
  for (int idx = tid; idx < 768; idx += 256) {
    int k = idx / 24, j = idx - k * 24;
    qfwT[idx] = qfw[j * 32 + k];
    rfwT[idx] = rfw[j * 32 + k];
  }
  for (int idx = tid; idx < 128; idx += 256) {
    dbs[idx] = dbih[idx] + dbhh[idx];
    qbs[idx] = qbih[idx] + qbhh[idx];
    rbs[idx] = rbih[idx] + rbhh[idx];
  }
  __syncthreads();
  int lane = tid & 63, w = tid >> 6, b = blockIdx.x * 4 + w;
  float* tL = tL4 + w * 120;
  int xl = (lane & 31) + 32;
  int l12 = lane < 12 ? lane : 0;
  int l24 = lane < 24 ? lane : 0;
  float cc = 0.f, hh = 0.f;
  if (lane < 32) {
    hh = dh0[b * 32 + lane];
    cc = dc0[b * 32 + lane];
  }
  float aReg[5];
  // decoder: 5 steps
#pragma unroll 1
  for (int s = 0; s < 5; ++s) {
    float ga = dbs[lane], gb2 = dbs[lane + 64];
#pragma unroll
    for (int k = 0; k < 32; ++k) {
      float hk = __shfl(hh, k);
      ga += hk * dwT[k * 128 + lane];
      gb2 += hk * dwT[k * 128 + lane + 64];
    }
    float gaX = __shfl(ga, xl);
    float gbX = __shfl(gb2, xl);
    if (lane < 32) {
      float ig = sigf(ga), fg = sigf(gaX);
      float gg = tanhf2(gb2), og = sigf(gbX);
      cc = fg * cc + ig * gg;
      hh = og * tanhf2(cc);
    }
    float pa = ob[l12];
#pragma unroll
    for (int k = 0; k < 32; ++k) pa += __shfl(hh, k) * owT[k * 12 + l12];
    aReg[s] = pa;
  }
  // physics integration -> tL (traj)
  if (lane < 12) {
    int n = lane >> 1, d = lane & 1;
    float v0 = 0.f, p0 = 0.f;
    if (n == 0) {
      p0 = obs[(size_t)b * 40000 + 39600 + d];
      v0 = obs[(size_t)b * 40000 + 39600 + 2 + d];
    }
    float vc = v0, pc = p0;
#pragma unroll
    for (int s = 0; s < 5; ++s) {
      float a = aReg[s];
      vc += 0.1f * a;
      pc += vc * 0.1f + a * 0.005f;
      tL[s * 24 + n * 4 + d] = pc;
      tL[s * 24 + n * 4 + 2 + d] = vc;
    }
  }
  __syncthreads();
#pragma unroll
  for (int e = 0; e < 2; ++e) {
    int idx = lane + 64 * e;
    if (idx < 120) traj[(size_t)b * 120 + idx] = tL[idx];
  }
  // Q then R LSTM over traj
#pragma unroll 1
  for (int qr = 0; qr < 2; ++qr) {
    const float* ihT = qr ? rihT : qihT;
    const float* hhT = qr ? rhhT : qhhT;
    const float* bs = qr ? rbs : qbs;
    const float* fwT = qr ? rfwT : qfwT;
    const float* fbg = qr ? rfb : qfb;
    float* outg = qr ? rdg : qdg;
    hh = 0.f;
    cc = 0.f;
#pragma unroll 1
    for (int s = 0; s < 5; ++s) {
      float ga = bs[lane], gb2 = bs[lane + 64];
#pragma unroll
      for (int k = 0; k < 24; ++k) {
        float z = tL[s * 24 + k];
        ga += z * ihT[k * 128 + lane];
        gb2 += z * ihT[k * 128 + lane + 64];
      }
#pragma unroll
      for (int k = 0; k < 32; ++k) {
        float hk = __shfl(hh, k);
        ga += hk * hhT[k * 128 + lane];
        gb2 += hk * hhT[k * 128 + lane + 64];
      }
      float gaX = __shfl(ga, xl);
      float gbX = __shfl(gb2, xl);
      if (lane < 32) {
        float ig = sigf(ga), fg = sigf(gaX);
        float gg = tanhf2(gb2), og = sigf(gbX);
        cc = fg * cc + ig * gg;
        hh = og * tanhf2(cc);
      }
    }
    float qv = fbg[l24];
#pragma unroll
    for (int k = 0; k < 32; ++k) qv += __shfl(hh, k) * fwT[k * 24 + l24];
    if (lane < 24) outg[b * 24 + lane] = fabsf(qv);
  }
}

// ================= K6: Kalman filter, register-resident, one wave/batch ===
// Column-per-lane layout: lane j<24 holds P column j; aug matrix [S | Pm]
// columns on lanes 0..47. All cross-lane via __shfl; no LDS, no barriers.
// Uses S = Pm + diag(R) symmetric => solve(S,Pm^T) = S^{-1} Pm.
__global__ __launch_bounds__(64, 1)
void k6_kf(const float* __restrict__ obs, const float* __restrict__ traj,
           const float* __restrict__ qd, const float* __restrict__ rd,
           float* __restrict__ out) {
  int lane = threadIdx.x;
  int b = blockIdx.x;
  int l24 = (lane < 24) ? lane : 0;
  float sv = 0.f, qv = 0.f, rv = 0.f;
  if (lane < 24) {
    sv = (lane < 4) ? obs[(size_t)b * 40000 + 39600 + lane] : 0.f;
    qv = qd[b * 24 + lane];
    rv = rd[b * 24 + lane];
  }
  float p[24];
#pragma unroll
  for (int i = 0; i < 24; ++i) p[i] = (i == lane) ? 1.f : 0.f;
  const int srcPF = ((lane & 3) < 2) ? (lane + 2) : lane;  // in-range for all 64 lanes
  const int srcA = (lane < 24) ? lane : (lane - 24);
#pragma unroll 1
  for (int s = 0; s < 5; ++s) {
    // ---- s_m = F s ----
    float sshift = __shfl(sv, srcPF);
    float smv = sv + (((lane & 3) < 2) ? 0.1f * sshift : 0.f);
    // ---- P <- F P (row update, lane-local) ----
#pragma unroll
    for (int i = 0; i < 24; ++i)
      if ((i & 3) < 2) p[i] += 0.1f * p[i + 2];
    // ---- P <- P F^T (column update via shfl from col j+2) ----
#pragma unroll
    for (int i = 0; i < 24; ++i) {
      float t = __shfl(p[i], srcPF);
      if ((lane & 3) < 2) p[i] += 0.1f * t;
    }
    // ---- + Qm (diagonal) ----
#pragma unroll
    for (int i = 0; i < 24; ++i) p[i] += (i == lane) ? qv : 0.f;
    // ---- build aug [S | Pm]: lanes<24 S col, lanes 24..47 Pm col ----
    float a[24];
#pragma unroll
    for (int i = 0; i < 24; ++i) {
      float t = __shfl(p[i], srcA);
      a[i] = (lane < 24) ? (p[i] + ((i == lane) ? rv : 0.f)) : t;
    }
    // ---- Gauss-Jordan, no pivoting (S SPD) ----
#pragma unroll
    for (int k = 0; k < 24; ++k) {
      float piv = __shfl(a[k], k);
      float inv = 1.f / piv;
      float t = a[k] * inv;   // new row-k element in this column
#pragma unroll
      for (int i = 0; i < 24; ++i) {
        if (i != k) {
          float fi = __shfl(a[i], k);  // old ag[i][k] (lane k not yet updated)
          a[i] = fmaf(-fi, t, a[i]);
        }
      }
      a[k] = t;
    }
    // lanes 24+j now hold X = S^{-1} Pm column j;  K = X^T
    // ---- innovation & state update ----
    float zv = traj[(size_t)b * 120 + s * 24 + l24];
    float innv = zv - smv;  // valid on lanes<24 (shfl sources)
    float acc = 0.f;
#pragma unroll
    for (int m = 0; m < 24; ++m) acc += a[m] * __shfl(innv, m);
    float kupd = __shfl(acc, 24 + l24);  // lane i<24 pulls from lane 24+i
    sv = smv + kupd;
    if (lane < 24) out[(size_t)b * 120 + s * 24 + lane] = sv;
    // ---- P_new = Pm - X^T Pm : pn[i] = p[i] - sum_k X[k][i]*p[k] ----
    float pn[24];
#pragma unroll
    for (int i = 0; i < 24; ++i) {
      float acc2 = 0.f;
#pragma unroll
      for (int k = 0; k < 24; ++k) acc2 += __shfl(a[k], 24 + i) * p[k];
      pn[i] = p[i] - acc2;
    }
#pragma unroll
    for (int i = 0; i < 24; ++i) p[i] = pn[i];
  }
}

// =========================================================================
extern "C" void kernel_launch(void* const* d_in, const int* in_sizes, int n_in,
                              void* d_out, int out_size, void* d_ws, size_t ws_size,
                              hipStream_t stream) {
  (void)in_sizes; (void)n_in; (void)out_size; (void)ws_size;
  const float* obs  = (const float*)d_in[0];
  const float* c1w  = (const float*)d_in[1];
  const float* c1b  = (const float*)d_in[2];
  const float* c2w  = (const float*)d_in[3];
  const float* c2b  = (const float*)d_in[4];
  const float* f1w  = (const float*)d_in[5];
  const float* f1b  = (const float*)d_in[6];
  const float* bn1g = (const float*)d_in[7];
  const float* bn1b = (const float*)d_in[8];
  const float* f2w  = (const float*)d_in[9];
  const float* f2b  = (const float*)d_in[10];
  const float* bn2g = (const float*)d_in[11];
  const float* bn2b = (const float*)d_in[12];
  const float* eWih = (const float*)d_in[13];
  const float* eWhh = (const float*)d_in[14];
  const float* ebih = (const float*)d_in[15];
  const float* ebhh = (const float*)d_in[16];
  const float* dWih = (const float*)d_in[17];
  const float* dWhh = (const float*)d_in[18];
  const float* dbih = (const float*)d_in[19];
  const float* dbhh = (const float*)d_in[20];
  const float* ow   = (const float*)d_in[21];
  const float* ob   = (const float*)d_in[22];
  const float* qWih = (const float*)d_in[23];
  const float* qWhh = (const float*)d_in[24];
  const float* qbih = (const float*)d_in[25];
  const float* qbhh = (const float*)d_in[26];
  const float* qfw  = (const float*)d_in[27];
  const float* qfb  = (const float*)d_in[28];
  const float* rWih = (const float*)d_in[29];
  const float* rWhh = (const float*)d_in[30];
  const float* rbih = (const float*)d_in[31];
  const float* rbhh = (const float*)d_in[32];
  const float* rfw  = (const float*)d_in[33];
  const float* rfb  = (const float*)d_in[34];

  float* ws = (float*)d_ws;
  float* p1   = ws + P1_OFF;
  float* x    = ws + X_OFF;
  float* gx   = ws + GX_OFF;       // reuses p1 region (dead after k2)
  float* dh   = ws + SM_OFF;
  float* dc   = dh + 16384;
  float* traj = dh + 32768;
  float* qdg  = dh + 94208;
  float* rdg  = dh + 106496;
  float* out  = (float*)d_out;

  k1_conv1<<<800, 512, 0, stream>>>(obs, c1w, c1b, p1);
  k2_conv2<<<dim3(200, 4), 256, 0, stream>>>(p1, c2w, c2b, x);
  k3_fc<<<800, 256, 0, stream>>>(x, f1w, f1b, bn1g, bn1b, f2w, f2b, bn2g, bn2b,
                                 eWih, ebih, ebhh, gx);
  k4_enc<<<512, 64, 0, stream>>>(gx, eWhh, dh, dc);
  k5_dec<<<128, 256, 0, stream>>>(obs, dWih, dWhh, dbih, dbhh, ow, ob,
                                  qWih, qWhh, qbih, qbhh, qfw, qfb,
                                  rWih, rWhh, rbih, rbhh, rfw, rfb,
                                  dh, dc, traj, qdg, rdg);
  k6_kf<<<512, 64, 0, stream>>>(obs, traj, qdg, rdg, out);
}

// Round 5
// 721.808 us; speedup vs baseline: 1.1269x; 1.0150x over previous
//
#include <hip/hip_runtime.h>

#define BT 51200      // B*T
#define NB 512        // batch

// ---------- workspace float offsets ----------
#define P1_OFF   ((size_t)0)
#define X_OFF    ((size_t)20480000)
#define GX_OFF   ((size_t)0)
#define SM_OFF   ((size_t)27033600)

__device__ __forceinline__ float sigf(float x) {
  return __fdividef(1.f, 1.f + __expf(-x));
}
__device__ __forceinline__ float tanhf2(float x) {
  float ax = fabsf(x);
  float e = __expf(-2.f * ax);
  float r = __fdividef(1.f - e, 1.f + e);
  return x < 0.f ? -r : r;
}

// ================= K1: conv1 (SAME 3x3, C=4->16) + relu + 2x2 maxpool =====
// Round-4 structure (clean memory: WRITE 91MB, FETCH 44MB, no spill) but
// 1024 threads / 16 waves, ONE output channel per wave (was 512/8/2oc).
// LDS (102.9KB) pins 1 block/CU either way; waves/block is the free axis:
// 16 waves/CU = 4/SIMD doubles latency hiding. Per-thread acc halves
// (40->20 regs) so peak live ~105 VGPR, comfortably under the 128 needed
// for 4 waves/SIMD. LDS-read traffic doubles (38us floor) - still under
// the FMA+latency budget. Rolling 6x12 row window unchanged.
__global__ __launch_bounds__(1024, 1)
void k1_conv1(const float* __restrict__ obs, const float* __restrict__ w,
              const float* __restrict__ bias, float* __restrict__ p1) {
  __shared__ float xs[64 * 401];
  int tid = threadIdx.x;
  int i0 = blockIdx.x * 64;
  // staging: same pattern as round 0/4 (FETCH 44MB, 25600 conflicts)
  for (int idx = tid; idx < 25600; idx += 1024) {
    int item = idx / 400, feat = idx - item * 400;
    xs[item * 401 + feat] = obs[(size_t)(i0 + item) * 400 + feat];
  }
  __syncthreads();
  int lane = tid & 63;
  int wv = __builtin_amdgcn_readfirstlane(tid >> 6);  // 0..15 = output channel
  const float* xrow = xs + lane * 401;

// load one padded input row (c=C, row index RR within the 4-row band) into R
#define LOADR(R, C, RR) do { \
  int r_ = 2 * p - 1 + (RR); \
  R[0] = 0.f; R[11] = 0.f; \
  if (r_ >= 0 && r_ <= 9) { \
    _Pragma("unroll") \
    for (int j = 0; j < 10; ++j) R[j + 1] = xrow[(C) * 100 + r_ * 10 + j]; \
  } else { \
    _Pragma("unroll") \
    for (int j = 0; j < 10; ++j) R[j + 1] = 0.f; \
  } \
} while (0)

// one FMA unit: output-row-pair II of channel C from rows RA,RB,RC (90 FMA)
// weights via uniform pointer -> s_load -> SGPR operand in v_fma
#define FMAU(II, RA, RB, RC, C) do { \
  const float* wa_ = w + wv * 36 + (C) * 9; \
  _Pragma("unroll") \
  for (int q = 0; q < 5; ++q) { \
    _Pragma("unroll") \
    for (int jj = 0; jj < 2; ++jj) { \
      int cb = 2 * q + jj; \
      acc[q][II][jj] += RA[cb] * wa_[0] + RA[cb + 1] * wa_[1] + RA[cb + 2] * wa_[2] \
                      + RB[cb] * wa_[3] + RB[cb + 1] * wa_[4] + RB[cb + 2] * wa_[5] \
                      + RC[cb] * wa_[6] + RC[cb + 1] * wa_[7] + RC[cb + 2] * wa_[8]; \
    } \
  } \
} while (0)

  float b0 = bias[wv];

#pragma unroll 1
  for (int p = 0; p < 5; ++p) {
    float acc[5][2][2];
#pragma unroll
    for (int q = 0; q < 5; ++q)
#pragma unroll
      for (int ii = 0; ii < 2; ++ii)
#pragma unroll
        for (int jj = 0; jj < 2; ++jj) acc[q][ii][jj] = b0;
    float R0[12], R1[12], R2[12], R3[12], R4[12], R5[12];
    // stream s0..s15 = (c0,r0..3)(c1,r0..3)(c2,r0..3)(c3,r0..3), buf = s%6
    LOADR(R0, 0, 0); LOADR(R1, 0, 1); LOADR(R2, 0, 2);  // s0,s1,s2
    LOADR(R3, 0, 3); LOADR(R4, 1, 0);                   // s3,s4
    FMAU(0, R0, R1, R2, 0);                             // U0
    LOADR(R5, 1, 1); LOADR(R0, 1, 2);                   // s5,s6
    FMAU(1, R1, R2, R3, 0);                             // U1
    LOADR(R1, 1, 3); LOADR(R2, 2, 0);                   // s7,s8
    FMAU(0, R4, R5, R0, 1);                             // U2
    LOADR(R3, 2, 1); LOADR(R4, 2, 2);                   // s9,s10
    FMAU(1, R5, R0, R1, 1);                             // U3
    LOADR(R5, 2, 3); LOADR(R0, 3, 0);                   // s11,s12
    FMAU(0, R2, R3, R4, 2);                             // U4
    LOADR(R1, 3, 1); LOADR(R2, 3, 2);                   // s13,s14
    FMAU(1, R3, R4, R5, 2);                             // U5
    LOADR(R3, 3, 3);                                    // s15
    FMAU(0, R0, R1, R2, 3);                             // U6
    FMAU(1, R1, R2, R3, 3);                             // U7
    // 2x2 maxpool + relu + store (256B segments per (p,q))
#pragma unroll
    for (int q = 0; q < 5; ++q) {
      float m = fmaxf(fmaxf(acc[q][0][0], acc[q][0][1]),
                      fmaxf(acc[q][1][0], acc[q][1][1]));
      m = fmaxf(m, 0.f);
      p1[(size_t)(wv * 25 + p * 5 + q) * BT + i0 + lane] = m;
    }
  }
#undef LOADR
#undef FMAU
}

// ================= K2: conv2 (SAME 3x3, 16->32) + relu + 2x2 maxpool ======
__global__ __launch_bounds__(256, 2)
void k2_conv2(const float* __restrict__ p1, const float* __restrict__ w,
              const float* __restrict__ bias, float* __restrict__ x) {
  int item = blockIdx.x * 256 + threadIdx.x;
  int oc = blockIdx.y;
  float acc[8][16];
#pragma unroll
  for (int o = 0; o < 8; ++o) {
    float bv = bias[oc * 8 + o];
#pragma unroll
    for (int pos = 0; pos < 16; ++pos) acc[o][pos] = bv;
  }
#pragma unroll 1
  for (int c = 0; c < 16; ++c) {
    float in[6][6];
#pragma unroll
    for (int t = 0; t < 6; ++t) { in[0][t] = 0.f; in[t][0] = 0.f; }
#pragma unroll
    for (int i = 0; i < 5; ++i)
#pragma unroll
      for (int j = 0; j < 5; ++j)
        in[i + 1][j + 1] = p1[(size_t)(c * 25 + i * 5 + j) * BT + item];
#pragma unroll
    for (int o = 0; o < 8; ++o) {
#pragma unroll
      for (int i = 0; i < 4; ++i)
#pragma unroll
        for (int j = 0; j < 4; ++j) {
          float a = acc[o][i * 4 + j];
#pragma unroll
          for (int dr = 0; dr < 3; ++dr)
#pragma unroll
            for (int dj = 0; dj < 3; ++dj)
              a += in[i + dr][j + dj] * w[((oc * 8 + o) * 16 + c) * 9 + dr * 3 + dj];
          acc[o][i * 4 + j] = a;
        }
    }
  }
#pragma unroll
  for (int o = 0; o < 8; ++o)
#pragma unroll
    for (int p = 0; p < 2; ++p)
#pragma unroll
      for (int q = 0; q < 2; ++q) {
        float m = fmaxf(fmaxf(acc[o][(2 * p) * 4 + 2 * q], acc[o][(2 * p) * 4 + 2 * q + 1]),
                        fmaxf(acc[o][(2 * p + 1) * 4 + 2 * q], acc[o][(2 * p + 1) * 4 + 2 * q + 1]));
        m = fmaxf(m, 0.f);
        x[(size_t)((oc * 8 + o) * 4 + p * 2 + q) * BT + item] = m;
      }
}

// ================= K3: fc1(+bn,relu) -> fc2(+bn,relu) -> eWih projection ===
__global__ __launch_bounds__(256, 2)
void k3_fc(const float* __restrict__ x,
           const float* __restrict__ f1w, const float* __restrict__ f1b,
           const float* __restrict__ bn1g, const float* __restrict__ bn1b,
           const float* __restrict__ f2w, const float* __restrict__ f2b,
           const float* __restrict__ bn2g, const float* __restrict__ bn2b,
           const float* __restrict__ eWih, const float* __restrict__ ebih,
           const float* __restrict__ ebhh, float* __restrict__ gx) {
  __shared__ float xs[128 * 64];
  __shared__ float ys[128 * 64];
  const float BNRS = 0.9999950000374997f;  // 1/sqrt(1+1e-5)
  int tid = threadIdx.x;
  int lane = tid & 63;
  int wv = __builtin_amdgcn_readfirstlane(tid >> 6);
  int i0 = blockIdx.x * 64;
#pragma unroll
  for (int r = 0; r < 32; ++r) {
    int k = r * 4 + (tid >> 6);
    xs[k * 64 + lane] = x[(size_t)k * BT + i0 + lane];
  }
  __syncthreads();
#pragma unroll 1
  for (int jj = 0; jj < 8; ++jj) {
    int j0 = wv * 32 + jj * 4;
    float a[4] = {0.f, 0.f, 0.f, 0.f};
#pragma unroll 8
    for (int k = 0; k < 128; ++k) {
      float xv = xs[k * 64 + lane];
#pragma unroll
      for (int u = 0; u < 4; ++u) a[u] += xv * f1w[(j0 + u) * 128 + k];
    }
#pragma unroll
    for (int u = 0; u < 4; ++u) {
      int j = j0 + u;
      float v = a[u] + f1b[j];
      v = bn1g[j] * v * BNRS + bn1b[j];
      ys[j * 64 + lane] = fmaxf(v, 0.f);
    }
  }
  __syncthreads();
#pragma unroll 1
  for (int jj = 0; jj < 4; ++jj) {
    int j0 = wv * 16 + jj * 4;
    float a[4] = {0.f, 0.f, 0.f, 0.f};
#pragma unroll 8
    for (int k = 0; k < 128; ++k) {
      float yv = ys[k * 64 + lane];
#pragma unroll
      for (int u = 0; u < 4; ++u) a[u] += yv * f2w[(j0 + u) * 128 + k];
    }
#pragma unroll
    for (int u = 0; u < 4; ++u) {
      int j = j0 + u;
      float v = a[u] + f2b[j];
      v = bn2g[j] * v * BNRS + bn2b[j];
      xs[j * 64 + lane] = fmaxf(v, 0.f);
    }
  }
  __syncthreads();
#pragma unroll 1
  for (int jj = 0; jj < 8; ++jj) {
    int j0 = wv * 32 + jj * 4;
    float a[4] = {0.f, 0.f, 0.f, 0.f};
#pragma unroll 8
    for (int k = 0; k < 64; ++k) {
      float zv = xs[k * 64 + lane];
#pragma unroll
      for (int u = 0; u < 4; ++u) a[u] += zv * eWih[(j0 + u) * 64 + k];
    }
#pragma unroll
    for (int u = 0; u < 4; ++u) {
      int j = j0 + u;
      gx[(size_t)j * BT + i0 + lane] = a[u] + ebih[j] + ebhh[j];
    }
  }
}

// ================= K4: encoder LSTM (T=100), one wave per batch ===========
__global__ __launch_bounds__(64, 4)
void k4_enc(const float* __restrict__ gx, const float* __restrict__ eWhh,
            float* __restrict__ dh, float* __restrict__ dc) {
  __shared__ float wT[32 * 128];  // [k][gate]
  int lane = threadIdx.x;
  int b = blockIdx.x;
#pragma unroll 1
  for (int r = 0; r < 64; ++r) {
    int idx = lane + r * 64;
    int g = idx & 127, k = idx >> 7;
    wT[k * 128 + g] = eWhh[g * 32 + k];
  }
  __syncthreads();
  float c = 0.f, h = 0.f;
  size_t base0 = (size_t)b * 100;
  float ga_n = gx[(size_t)lane * BT + base0];
  float gb_n = gx[(size_t)(lane + 64) * BT + base0];
  int xl = (lane & 31) + 32;
#pragma unroll 1
  for (int t = 0; t < 100; ++t) {
    float ga = ga_n, gb2 = gb_n;
    if (t < 99) {
      ga_n = gx[(size_t)lane * BT + base0 + t + 1];
      gb_n = gx[(size_t)(lane + 64) * BT + base0 + t + 1];
    }
#pragma unroll
    for (int k = 0; k < 32; ++k) {
      float hk = __shfl(h, k);
      ga += hk * wT[k * 128 + lane];
      gb2 += hk * wT[k * 128 + lane + 64];
    }
    float gaX = __shfl(ga, xl);   // gate lane+32 (f for lanes<32)
    float gbX = __shfl(gb2, xl);  // gate lane+96 (o for lanes<32)
    if (lane < 32) {
      float ig = sigf(ga);
      float fg = sigf(gaX);
      float gg = tanhf2(gb2);
      float og = sigf(gbX);
      c = fg * c + ig * gg;
      h = og * tanhf2(c);
    }
  }
  if (lane < 32) {
    dh[b * 32 + lane] = h;
    dc[b * 32 + lane] = c;
  }
}

// ====== K5: decoder LSTM (din==dh identity) + physics + Q/R LSTMs =========
__global__ __launch_bounds__(256, 2)
void k5_dec(const float* __restrict__ obs,
            const float* __restrict__ dWih, const float* __restrict__ dWhh,
            const float* __restrict__ dbih, const float* __restrict__ dbhh,
            const float* __restrict__ ow, const float* __restrict__ ob,
            const float* __restrict__ qWih, const float* __restrict__ qWhh,
            const float* __restrict__ qbih, const float* __restrict__ qbhh,
            const float* __restrict__ qfw, const float* __restrict__ qfb,
            const float* __restrict__ rWih, const float* __restrict__ rWhh,
            const float* __restrict__ rbih, const float* __restrict__ rbhh,
            const float* __restrict__ rfw, const float* __restrict__ rfb,
            const float* __restrict__ dh0, const float* __restrict__ dc0,
            float* __restrict__ traj, float* __restrict__ qdg, float* __restrict__ rdg) {
  __shared__ float dwT[32 * 128], qihT[24 * 128], qhhT[32 * 128], rihT[24 * 128], rhhT[32 * 128];
  __shared__ float owT[32 * 12], qfwT[32 * 24], rfwT[32 * 24];
  __shared__ float dbs[128], qbs[128], rbs[128];
  __shared__ float tL4[4 * 120];
  int tid = threadIdx.x;
  for (int idx = tid; idx < 4096; idx += 256) {
    int k = idx >> 7, g = idx & 127;
    dwT[idx] = dWih[g * 32 + k] + dWhh[g * 32 + k];  // din==dh every step
    qhhT[idx] = qWhh[g * 32 + k];
    rhhT[idx] = rWhh[g * 32 + k];
  }
  for (int idx = tid; idx < 3072; idx += 256) {
    int k = idx >> 7, g = idx & 127;
    qihT[idx] = qWih[g * 24 + k];
    rihT[idx] = rWih[g * 24 + k];
  }
  for (int idx = tid; idx < 384; idx += 256) {
    int k = idx / 12, j = idx - k * 12;
    owT[idx] = ow[j * 32 + k];
  }
  for (int idx = tid; idx < 768; idx += 256) {
    int k = idx / 24, j = idx - k * 24;
    qfwT[idx] = qfw[j * 32 + k];
    rfwT[idx] = rfw[j * 32 + k];
  }
  for (int idx = tid; idx < 128; idx += 256) {
    dbs[idx] = dbih[idx] + dbhh[idx];
    qbs[idx] = qbih[idx] + qbhh[idx];
    rbs[idx] = rbih[idx] + rbhh[idx];
  }
  __syncthreads();
  int lane = tid & 63, w = tid >> 6, b = blockIdx.x * 4 + w;
  float* tL = tL4 + w * 120;
  int xl = (lane & 31) + 32;
  int l12 = lane < 12 ? lane : 0;
  int l24 = lane < 24 ? lane : 0;
  float cc = 0.f, hh = 0.f;
  if (lane < 32) {
    hh = dh0[b * 32 + lane];
    cc = dc0[b * 32 + lane];
  }
  float aReg[5];
  // decoder: 5 steps
#pragma unroll 1
  for (int s = 0; s < 5; ++s) {
    float ga = dbs[lane], gb2 = dbs[lane + 64];
#pragma unroll
    for (int k = 0; k < 32; ++k) {
      float hk = __shfl(hh, k);
      ga += hk * dwT[k * 128 + lane];
      gb2 += hk * dwT[k * 128 + lane + 64];
    }
    float gaX = __shfl(ga, xl);
    float gbX = __shfl(gb2, xl);
    if (lane < 32) {
      float ig = sigf(ga), fg = sigf(gaX);
      float gg = tanhf2(gb2), og = sigf(gbX);
      cc = fg * cc + ig * gg;
      hh = og * tanhf2(cc);
    }
    float pa = ob[l12];
#pragma unroll
    for (int k = 0; k < 32; ++k) pa += __shfl(hh, k) * owT[k * 12 + l12];
    aReg[s] = pa;
  }
  // physics integration -> tL (traj)
  if (lane < 12) {
    int n = lane >> 1, d = lane & 1;
    float v0 = 0.f, p0 = 0.f;
    if (n == 0) {
      p0 = obs[(size_t)b * 40000 + 39600 + d];
      v0 = obs[(size_t)b * 40000 + 39600 + 2 + d];
    }
    float vc = v0, pc = p0;
#pragma unroll
    for (int s = 0; s < 5; ++s) {
      float a = aReg[s];
      vc += 0.1f * a;
      pc += vc * 0.1f + a * 0.005f;
      tL[s * 24 + n * 4 + d] = pc;
      tL[s * 24 + n * 4 + 2 + d] = vc;
    }
  }
  __syncthreads();
#pragma unroll
  for (int e = 0; e < 2; ++e) {
    int idx = lane + 64 * e;
    if (idx < 120) traj[(size_t)b * 120 + idx] = tL[idx];
  }
  // Q then R LSTM over traj
#pragma unroll 1
  for (int qr = 0; qr < 2; ++qr) {
    const float* ihT = qr ? rihT : qihT;
    const float* hhT = qr ? rhhT : qhhT;
    const float* bs = qr ? rbs : qbs;
    const float* fwT = qr ? rfwT : qfwT;
    const float* fbg = qr ? rfb : qfb;
    float* outg = qr ? rdg : qdg;
    hh = 0.f;
    cc = 0.f;
#pragma unroll 1
    for (int s = 0; s < 5; ++s) {
      float ga = bs[lane], gb2 = bs[lane + 64];
#pragma unroll
      for (int k = 0; k < 24; ++k) {
        float z = tL[s * 24 + k];
        ga += z * ihT[k * 128 + lane];
        gb2 += z * ihT[k * 128 + lane + 64];
      }
#pragma unroll
      for (int k = 0; k < 32; ++k) {
        float hk = __shfl(hh, k);
        ga += hk * hhT[k * 128 + lane];
        gb2 += hk * hhT[k * 128 + lane + 64];
      }
      float gaX = __shfl(ga, xl);
      float gbX = __shfl(gb2, xl);
      if (lane < 32) {
        float ig = sigf(ga), fg = sigf(gaX);
        float gg = tanhf2(gb2), og = sigf(gbX);
        cc = fg * cc + ig * gg;
        hh = og * tanhf2(cc);
      }
    }
    float qv = fbg[l24];
#pragma unroll
    for (int k = 0; k < 32; ++k) qv += __shfl(hh, k) * fwT[k * 24 + l24];
    if (lane < 24) outg[b * 24 + lane] = fabsf(qv);
  }
}

// ================= K6: Kalman filter, register-resident, one wave/batch ===
// Column-per-lane layout: lane j<24 holds P column j; aug matrix [S | Pm]
// columns on lanes 0..47. All cross-lane via __shfl; no LDS, no barriers.
// Uses S = Pm + diag(R) symmetric => solve(S,Pm^T) = S^{-1} Pm.
__global__ __launch_bounds__(64, 1)
void k6_kf(const float* __restrict__ obs, const float* __restrict__ traj,
           const float* __restrict__ qd, const float* __restrict__ rd,
           float* __restrict__ out) {
  int lane = threadIdx.x;
  int b = blockIdx.x;
  int l24 = (lane < 24) ? lane : 0;
  float sv = 0.f, qv = 0.f, rv = 0.f;
  if (lane < 24) {
    sv = (lane < 4) ? obs[(size_t)b * 40000 + 39600 + lane] : 0.f;
    qv = qd[b * 24 + lane];
    rv = rd[b * 24 + lane];
  }
  float p[24];
#pragma unroll
  for (int i = 0; i < 24; ++i) p[i] = (i == lane) ? 1.f : 0.f;
  const int srcPF = ((lane & 3) < 2) ? (lane + 2) : lane;  // in-range for all 64 lanes
  const int srcA = (lane < 24) ? lane : (lane - 24);
#pragma unroll 1
  for (int s = 0; s < 5; ++s) {
    // ---- s_m = F s ----
    float sshift = __shfl(sv, srcPF);
    float smv = sv + (((lane & 3) < 2) ? 0.1f * sshift : 0.f);
    // ---- P <- F P (row update, lane-local) ----
#pragma unroll
    for (int i = 0; i < 24; ++i)
      if ((i & 3) < 2) p[i] += 0.1f * p[i + 2];
    // ---- P <- P F^T (column update via shfl from col j+2) ----
#pragma unroll
    for (int i = 0; i < 24; ++i) {
      float t = __shfl(p[i], srcPF);
      if ((lane & 3) < 2) p[i] += 0.1f * t;
    }
    // ---- + Qm (diagonal) ----
#pragma unroll
    for (int i = 0; i < 24; ++i) p[i] += (i == lane) ? qv : 0.f;
    // ---- build aug [S | Pm]: lanes<24 S col, lanes 24..47 Pm col ----
    float a[24];
#pragma unroll
    for (int i = 0; i < 24; ++i) {
      float t = __shfl(p[i], srcA);
      a[i] = (lane < 24) ? (p[i] + ((i == lane) ? rv : 0.f)) : t;
    }
    // ---- Gauss-Jordan, no pivoting (S SPD) ----
#pragma unroll
    for (int k = 0; k < 24; ++k) {
      float piv = __shfl(a[k], k);
      float inv = 1.f / piv;
      float t = a[k] * inv;   // new row-k element in this column
#pragma unroll
      for (int i = 0; i < 24; ++i) {
        if (i != k) {
          float fi = __shfl(a[i], k);  // old ag[i][k] (lane k not yet updated)
          a[i] = fmaf(-fi, t, a[i]);
        }
      }
      a[k] = t;
    }
    // lanes 24+j now hold X = S^{-1} Pm column j;  K = X^T
    // ---- innovation & state update ----
    float zv = traj[(size_t)b * 120 + s * 24 + l24];
    float innv = zv - smv;  // valid on lanes<24 (shfl sources)
    float acc = 0.f;
#pragma unroll
    for (int m = 0; m < 24; ++m) acc += a[m] * __shfl(innv, m);
    float kupd = __shfl(acc, 24 + l24);  // lane i<24 pulls from lane 24+i
    sv = smv + kupd;
    if (lane < 24) out[(size_t)b * 120 + s * 24 + lane] = sv;
    // ---- P_new = Pm - X^T Pm : pn[i] = p[i] - sum_k X[k][i]*p[k] ----
    float pn[24];
#pragma unroll
    for (int i = 0; i < 24; ++i) {
      float acc2 = 0.f;
#pragma unroll
      for (int k = 0; k < 24; ++k) acc2 += __shfl(a[k], 24 + i) * p[k];
      pn[i] = p[i] - acc2;
    }
#pragma unroll
    for (int i = 0; i < 24; ++i) p[i] = pn[i];
  }
}

// =========================================================================
extern "C" void kernel_launch(void* const* d_in, const int* in_sizes, int n_in,
                              void* d_out, int out_size, void* d_ws, size_t ws_size,
                              hipStream_t stream) {
  (void)in_sizes; (void)n_in; (void)out_size; (void)ws_size;
  const float* obs  = (const float*)d_in[0];
  const float* c1w  = (const float*)d_in[1];
  const float* c1b  = (const float*)d_in[2];
  const float* c2w  = (const float*)d_in[3];
  const float* c2b  = (const float*)d_in[4];
  const float* f1w  = (const float*)d_in[5];
  const float* f1b  = (const float*)d_in[6];
  const float* bn1g = (const float*)d_in[7];
  const float* bn1b = (const float*)d_in[8];
  const float* f2w  = (const float*)d_in[9];
  const float* f2b  = (const float*)d_in[10];
  const float* bn2g = (const float*)d_in[11];
  const float* bn2b = (const float*)d_in[12];
  const float* eWih = (const float*)d_in[13];
  const float* eWhh = (const float*)d_in[14];
  const float* ebih = (const float*)d_in[15];
  const float* ebhh = (const float*)d_in[16];
  const float* dWih = (const float*)d_in[17];
  const float* dWhh = (const float*)d_in[18];
  const float* dbih = (const float*)d_in[19];
  const float* dbhh = (const float*)d_in[20];
  const float* ow   = (const float*)d_in[21];
  const float* ob   = (const float*)d_in[22];
  const float* qWih = (const float*)d_in[23];
  const float* qWhh = (const float*)d_in[24];
  const float* qbih = (const float*)d_in[25];
  const float* qbhh = (const float*)d_in[26];
  const float* qfw  = (const float*)d_in[27];
  const float* qfb  = (const float*)d_in[28];
  const float* rWih = (const float*)d_in[29];
  const float* rWhh = (const float*)d_in[30];
  const float* rbih = (const float*)d_in[31];
  const float* rbhh = (const float*)d_in[32];
  const float* rfw  = (const float*)d_in[33];
  const float* rfb  = (const float*)d_in[34];

  float* ws = (float*)d_ws;
  float* p1   = ws + P1_OFF;
  float* x    = ws + X_OFF;
  float* gx   = ws + GX_OFF;       // reuses p1 region (dead after k2)
  float* dh   = ws + SM_OFF;
  float* dc   = dh + 16384;
  float* traj = dh + 32768;
  float* qdg  = dh + 94208;
  float* rdg  = dh + 106496;
  float* out  = (float*)d_out;

  k1_conv1<<<800, 1024, 0, stream>>>(obs, c1w, c1b, p1);
  k2_conv2<<<dim3(200, 4), 256, 0, stream>>>(p1, c2w, c2b, x);
  k3_fc<<<800, 256, 0, stream>>>(x, f1w, f1b, bn1g, bn1b, f2w, f2b, bn2g, bn2b,
                                 eWih, ebih, ebhh, gx);
  k4_enc<<<512, 64, 0, stream>>>(gx, eWhh, dh, dc);
  k5_dec<<<128, 256, 0, stream>>>(obs, dWih, dWhh, dbih, dbhh, ow, ob,
                                  qWih, qWhh, qbih, qbhh, qfw, qfb,
                                  rWih, rWhh, rbih, rbhh, rfw, rfb,
                                  dh, dc, traj, qdg, rdg);
  k6_kf<<<512, 64, 0, stream>>>(obs, traj, qdg, rdg, out);
}